// Round 8
// baseline (2628.908 us; speedup 1.0000x reference)
//
#include <hip/hip_runtime.h>
#include <cstddef>

#define NN 100000
#define NE 1600000
#define D 128
#define D2 256
#define EF 7
#define NL 5
#define BN_EPS 1e-5f
#define NWAVE 25000
#define DBINS 512

typedef unsigned short ushort_t;
typedef __attribute__((ext_vector_type(8))) _Float16 f16x8;
typedef __attribute__((ext_vector_type(2))) _Float16 h2v;
typedef __attribute__((ext_vector_type(4))) float f32x4;

__device__ __forceinline__ void atomAddF(float* p, float v) { unsafeAtomicAdd(p, v); }

__device__ __forceinline__ ushort_t f2h(float f) {
    return __builtin_bit_cast(ushort_t, (_Float16)f);
}
__device__ __forceinline__ unsigned pk2h(float lo, float hi) {
    return (unsigned)f2h(lo) | ((unsigned)f2h(hi) << 16);
}
__device__ __forceinline__ float h2f(unsigned u16) {
    return (float)__builtin_bit_cast(_Float16, (ushort_t)(u16 & 0xFFFFu));
}
__device__ __forceinline__ h2v u2h2(unsigned u) { return __builtin_bit_cast(h2v, u); }

// ---------------- CSR build ----------------
__global__ __launch_bounds__(256)
void hist_kernel(const int* __restrict__ ei, int* __restrict__ counts)
{
    const int e = blockIdx.x * 256 + threadIdx.x;
    if (e < NE) atomicAdd(&counts[ei[NE + e]], 1);
}

__global__ __launch_bounds__(1024)
void scan_kernel(const int* __restrict__ counts, int* __restrict__ offs)
{
    __shared__ int ssum[1024];
    const int t = threadIdx.x;
    const int per = (NN + 1023) / 1024;
    const int base = t * per;
    int local = 0;
    for (int j = 0; j < per; ++j) {
        const int i = base + j;
        if (i < NN) local += counts[i];
    }
    ssum[t] = local;
    __syncthreads();
    for (int off = 1; off < 1024; off <<= 1) {
        int v = 0;
        if (t >= off) v = ssum[t - off];
        __syncthreads();
        ssum[t] += v;
        __syncthreads();
    }
    int run = ssum[t] - local;
    for (int j = 0; j < per; ++j) {
        const int i = base + j;
        if (i < NN) { offs[i] = run; run += counts[i]; }
    }
    if (t == 1023) offs[NN] = NE;
}

// scatter edges into dst-sorted order; pack edge features fp16 [8] (7 used)
__global__ __launch_bounds__(256)
void scatter_kernel(const int* __restrict__ ei, const float* __restrict__ ea,
                    int* __restrict__ offmut, int* __restrict__ sSrc,
                    ushort_t* __restrict__ eaH)
{
    const int e = blockIdx.x * 256 + threadIdx.x;
    if (e < NE) {
        const int dst = ei[NE + e];
        const int pos = atomicAdd(&offmut[dst], 1);
        sSrc[pos] = ei[e];
        const float* eap = &ea[(size_t)e * EF];
        const unsigned o0 = pk2h(eap[0], eap[1]);
        const unsigned o1 = pk2h(eap[2], eap[3]);
        const unsigned o2 = pk2h(eap[4], eap[5]);
        const unsigned o3 = pk2h(eap[6], 0.f);
        *(uint4*)&eaH[(size_t)pos * 8] = make_uint4(o0, o1, o2, o3);
    }
}

// ---------------- weight convert: W1[l][k][n]->W1t[l][n][k] fp16, W2 same ----------------
__global__ __launch_bounds__(256)
void wconv_kernel(const float* __restrict__ W1, const float* __restrict__ W2,
                  ushort_t* __restrict__ W1t, ushort_t* __restrict__ W2t)
{
    const int idx = blockIdx.x * 256 + threadIdx.x;
    const int per = D * D2;
    if (idx < NL * per) {
        const int l = idx / per, r = idx % per;
        const int k1 = r / D2, n1 = r % D2;            // W1: [128][256]
        W1t[(size_t)l * per + n1 * D + k1] = f2h(W1[idx]);
        const int k2 = r / D, n2 = r % D;              // W2: [256][128]
        W2t[(size_t)l * per + n2 * D2 + k2] = f2h(W2[idx]);
    }
}

// ---------------- degree sort: counting sort of nodes by degree ----------------
__global__ __launch_bounds__(256)
void dhist_kernel(const int* __restrict__ counts, int* __restrict__ dh)
{
    const int n = blockIdx.x * 256 + threadIdx.x;
    if (n < NN) atomicAdd(&dh[min(counts[n], DBINS - 1)], 1);
}

__global__ __launch_bounds__(DBINS)
void dscan_kernel(const int* __restrict__ dh, int* __restrict__ dbase)
{
    __shared__ int ss[DBINS];
    const int t = threadIdx.x;
    const int own = dh[t];
    ss[t] = own;
    __syncthreads();
    for (int off = 1; off < DBINS; off <<= 1) {
        int v = 0;
        if (t >= off) v = ss[t - off];
        __syncthreads();
        ss[t] += v;
        __syncthreads();
    }
    dbase[t] = ss[t] - own;   // exclusive
}

__global__ __launch_bounds__(256)
void dperm_kernel(const int* __restrict__ counts, int* __restrict__ dbase,
                  int* __restrict__ perm)
{
    const int n = blockIdx.x * 256 + threadIdx.x;
    if (n < NN) {
        const int rank = atomicAdd(&dbase[min(counts[n], DBINS - 1)], 1);
        perm[rank] = n;
    }
}

// ---------------- gather: xin[n] = (1+eps)*h(n) + sum_e relu(h(src)+ee) ----------------
// degree-sorted: wave handles 4 consecutive nodes in degree order; packed fp16 MLP.
template<int L0>
__global__ __launch_bounds__(256)
void gather_kernel(const int* __restrict__ offs, const int* __restrict__ sSrc,
                   const ushort_t* __restrict__ eaH, const int* __restrict__ perm,
                   const float* __restrict__ We, const float* __restrict__ be,
                   const ushort_t* __restrict__ hAct, const float* __restrict__ h0,
                   const float* __restrict__ epsp,
                   ushort_t* __restrict__ xinH, float* __restrict__ xsum)
{
    __shared__ __align__(16) float sCS[4][D];
    const int lane = threadIdx.x & 63;
    const int w = threadIdx.x >> 6;
    const int wid = blockIdx.x * 4 + w;
    // spread degree classes across dispatch order (9973 coprime with 25000)
    const int wids = (int)(((long long)wid * 9973) % NWAVE);

    const float2* We2 = (const float2*)We;
    const unsigned* hU = (const unsigned*)hAct;   // 64 dwords per row
    unsigned* xU = (unsigned*)xinH;
    h2v wP[EF];
    #pragma unroll
    for (int k = 0; k < EF; ++k) {
        const float2 wf = We2[k * 64 + lane];
        wP[k] = (h2v){(_Float16)wf.x, (_Float16)wf.y};
    }
    h2v beP;
    {
        const float2 bf = ((const float2*)be)[lane];
        beP = (h2v){(_Float16)bf.x, (_Float16)bf.y};
    }
    float2 h0v = {0.f, 0.f};
    h2v h0P = (h2v){(_Float16)0.f, (_Float16)0.f};
    if (L0) {
        h0v = ((const float2*)h0)[lane];
        h0P = (h2v){(_Float16)h0v.x, (_Float16)h0v.y};
    }
    const float epsv = 1.0f + *epsp;
    const h2v zz = (h2v){(_Float16)0.f, (_Float16)0.f};

    int nd[4], p4[4], e4[4];
    #pragma unroll
    for (int i = 0; i < 4; ++i) {
        nd[i] = __builtin_amdgcn_readfirstlane(perm[wids * 4 + i]);
        p4[i] = __builtin_amdgcn_readfirstlane(offs[nd[i]]);
        e4[i] = __builtin_amdgcn_readfirstlane(offs[nd[i] + 1]);
    }
    const int mx = max(max(e4[0] - p4[0], e4[1] - p4[1]),
                       max(e4[2] - p4[2], e4[3] - p4[3]));

    float2 acc[4];
    #pragma unroll
    for (int i = 0; i < 4; ++i) acc[i] = (float2){0.f, 0.f};

    for (int j = 0; j < mx; ++j) {
        unsigned hwd[4];
        uint4 ev4[4];
        bool on[4];
        #pragma unroll
        for (int i = 0; i < 4; ++i) {
            on[i] = p4[i] < e4[i];
            if (on[i]) {
                ev4[i] = *(const uint4*)&eaH[(size_t)p4[i] * 8];   // wave-uniform
                if (!L0) {
                    const int src = sSrc[p4[i]];                   // wave-uniform
                    hwd[i] = hU[(src << 6) + lane];
                }
            }
        }
        #pragma unroll
        for (int i = 0; i < 4; ++i) {
            if (on[i]) {
                const h2v e01 = u2h2(ev4[i].x);
                const h2v e23 = u2h2(ev4[i].y);
                const h2v e45 = u2h2(ev4[i].z);
                const h2v e6x = u2h2(ev4[i].w);
                h2v m = beP;
                m = __builtin_elementwise_fma(__builtin_shufflevector(e01, e01, 0, 0), wP[0], m);
                m = __builtin_elementwise_fma(__builtin_shufflevector(e01, e01, 1, 1), wP[1], m);
                m = __builtin_elementwise_fma(__builtin_shufflevector(e23, e23, 0, 0), wP[2], m);
                m = __builtin_elementwise_fma(__builtin_shufflevector(e23, e23, 1, 1), wP[3], m);
                m = __builtin_elementwise_fma(__builtin_shufflevector(e45, e45, 0, 0), wP[4], m);
                m = __builtin_elementwise_fma(__builtin_shufflevector(e45, e45, 1, 1), wP[5], m);
                m = __builtin_elementwise_fma(__builtin_shufflevector(e6x, e6x, 0, 0), wP[6], m);
                const h2v hh = L0 ? h0P : u2h2(hwd[i]);
                const h2v r = __builtin_elementwise_max(m + hh, zz);
                acc[i].x += (float)r.x;
                acc[i].y += (float)r.y;
                ++p4[i];
            }
        }
    }

    float2 cs = {0.f, 0.f};
    #pragma unroll
    for (int i = 0; i < 4; ++i) {
        const int n = nd[i];
        float2 hs;
        if (L0) hs = h0v;
        else {
            const unsigned hv = hU[(n << 6) + lane];
            hs.x = h2f(hv); hs.y = h2f(hv >> 16);
        }
        float2 a = acc[i];
        a.x = fmaf(epsv, hs.x, a.x);
        a.y = fmaf(epsv, hs.y, a.y);
        cs.x += a.x; cs.y += a.y;
        xU[(n << 6) + lane] = pk2h(a.x, a.y);
    }
    sCS[w][2 * lane] = cs.x;
    sCS[w][2 * lane + 1] = cs.y;
    __syncthreads();
    if (threadIdx.x < D) {
        atomAddF(&xsum[threadIdx.x],
                 sCS[0][threadIdx.x] + sCS[1][threadIdx.x] +
                 sCS[2][threadIdx.x] + sCS[3][threadIdx.x]);
    }
}

// ---------------- mm1: z1c = (xin - colmean) @ W1 (fp16 MFMA), fused stats ----------------
__global__ __launch_bounds__(256, 2)
void mm1_kernel(const ushort_t* __restrict__ xinH, const float* __restrict__ xsum,
                const ushort_t* __restrict__ W1t,
                ushort_t* __restrict__ z1H, float* __restrict__ stats)
{
    __shared__ __align__(16) ushort_t sA[64 * 128];
    __shared__ __align__(16) float sM[D];
    const int t = threadIdx.x;
    if (t < D) sM[t] = xsum[t] * (1.0f / (float)NN);
    const int i0 = blockIdx.x * 64;
    const int lane = t & 63, w = t >> 6;
    const int nb = w * 64;

    f16x8 bfr[4][4];
    #pragma unroll
    for (int nt = 0; nt < 4; ++nt)
        #pragma unroll
        for (int ks = 0; ks < 4; ++ks) {
            const int n = nb + nt * 16 + (lane & 15);
            const int k = ks * 32 + (lane >> 4) * 8;
            bfr[nt][ks] = *(const f16x8*)&W1t[n * D + k];
        }
    __syncthreads();   // sM visible

    #pragma unroll
    for (int p = 0; p < 4; ++p) {
        const int linear = p * 256 + t;
        const int row = linear >> 4, ch = linear & 15;
        const int gi = i0 + row;
        unsigned oo[4] = {0, 0, 0, 0};
        if (gi < NN) {
            const uint4 v = *(const uint4*)&xinH[(size_t)gi * D + ch * 8];
            const unsigned uu[4] = {v.x, v.y, v.z, v.w};
            #pragma unroll
            for (int j2 = 0; j2 < 4; ++j2) {
                const int c0 = ch * 8 + j2 * 2;
                oo[j2] = pk2h(h2f(uu[j2]) - sM[c0], h2f(uu[j2] >> 16) - sM[c0 + 1]);
            }
        }
        unsigned boff = (unsigned)(row * 256 + ch * 16);
        boff ^= (unsigned)((row & 7) << 4);
        *(uint4*)((char*)sA + boff) = make_uint4(oo[0], oo[1], oo[2], oo[3]);
    }
    __syncthreads();

    f32x4 acc[4][4];
    #pragma unroll
    for (int a = 0; a < 4; ++a)
        #pragma unroll
        for (int b = 0; b < 4; ++b) acc[a][b] = (f32x4){0.f, 0.f, 0.f, 0.f};

    #pragma unroll
    for (int mt = 0; mt < 4; ++mt) {
        f16x8 af[4];
        #pragma unroll
        for (int ks = 0; ks < 4; ++ks) {
            const int row = mt * 16 + (lane & 15);
            unsigned boff = (unsigned)(row * 256 + ks * 64 + (lane >> 4) * 16);
            boff ^= (unsigned)((row & 7) << 4);
            af[ks] = *(const f16x8*)((const char*)sA + boff);
        }
        #pragma unroll
        for (int nt = 0; nt < 4; ++nt)
            #pragma unroll
            for (int ks = 0; ks < 4; ++ks)
                acc[mt][nt] = __builtin_amdgcn_mfma_f32_16x16x32_f16(af[ks], bfr[nt][ks], acc[mt][nt], 0, 0, 0);
    }

    float s[4], q[4];
    #pragma unroll
    for (int nt = 0; nt < 4; ++nt) { s[nt] = 0.f; q[nt] = 0.f; }
    #pragma unroll
    for (int nt = 0; nt < 4; ++nt) {
        const int n = nb + nt * 16 + (lane & 15);
        #pragma unroll
        for (int mt = 0; mt < 4; ++mt)
            #pragma unroll
            for (int r = 0; r < 4; ++r) {
                const int i = i0 + mt * 16 + (lane >> 4) * 4 + r;
                if (i < NN) {
                    const float v = acc[mt][nt][r];
                    s[nt] += v; q[nt] = fmaf(v, v, q[nt]);
                    z1H[(size_t)i * D2 + n] = f2h(v);
                }
            }
    }
    #pragma unroll
    for (int nt = 0; nt < 4; ++nt) {
        s[nt] += __shfl_xor(s[nt], 16, 64); s[nt] += __shfl_xor(s[nt], 32, 64);
        q[nt] += __shfl_xor(q[nt], 16, 64); q[nt] += __shfl_xor(q[nt], 32, 64);
    }
    if (lane < 16) {
        #pragma unroll
        for (int nt = 0; nt < 4; ++nt) {
            const int n = nb + nt * 16 + lane;
            atomAddF(&stats[n], s[nt]);
            atomAddF(&stats[D2 + n], q[nt]);
        }
    }
}

// ---------------- ymean: ysum[c] = sum_rows relu(a*z1c+cc); aff computed inline ----------------
#define YROWS 391
__global__ __launch_bounds__(256)
void ymean_kernel(const ushort_t* __restrict__ z1H, const float* __restrict__ stats1,
                  const float* __restrict__ g1, const float* __restrict__ bt1,
                  float* __restrict__ ysum)
{
    __shared__ float sAf[2 * D2];
    __shared__ float sR[4][D2];
    const int t = threadIdx.x;
    {
        const float inv = 1.0f / (float)NN;
        const float mu = stats1[t] * inv;
        const float var = fmaf(-mu, mu, stats1[D2 + t] * inv);
        const float a = g1[t] * rsqrtf(var + BN_EPS);
        sAf[t] = a;
        sAf[D2 + t] = fmaf(-a, mu, bt1[t]);
    }
    __syncthreads();
    const int c0 = (t & 63) * 4;
    const int rg = t >> 6;
    const float a0 = sAf[c0], a1 = sAf[c0 + 1], a2 = sAf[c0 + 2], a3 = sAf[c0 + 3];
    const float b0 = sAf[D2 + c0], b1 = sAf[D2 + c0 + 1], b2 = sAf[D2 + c0 + 2], b3 = sAf[D2 + c0 + 3];
    float s0 = 0.f, s1 = 0.f, s2 = 0.f, s3 = 0.f;
    const int rend = min(NN, (blockIdx.x + 1) * YROWS);
    for (int r = blockIdx.x * YROWS + rg; r < rend; r += 4) {
        const uint2 v = *(const uint2*)&z1H[(size_t)r * D2 + c0];
        s0 += fmaxf(fmaf(a0, h2f(v.x), b0), 0.f);
        s1 += fmaxf(fmaf(a1, h2f(v.x >> 16), b1), 0.f);
        s2 += fmaxf(fmaf(a2, h2f(v.y), b2), 0.f);
        s3 += fmaxf(fmaf(a3, h2f(v.y >> 16), b3), 0.f);
    }
    sR[rg][c0] = s0; sR[rg][c0 + 1] = s1; sR[rg][c0 + 2] = s2; sR[rg][c0 + 3] = s3;
    __syncthreads();
    if (t < D2) atomAddF(&ysum[t], sR[0][t] + sR[1][t] + sR[2][t] + sR[3][t]);
}

// ---------------- mm2: z2c = (relu(aff1(z1c)) - ymean) @ W2 (fp16 MFMA), fp16 out ----------------
__global__ __launch_bounds__(256, 2)
void mm2_kernel(const ushort_t* __restrict__ z1H, const float* __restrict__ stats1,
                const float* __restrict__ g1, const float* __restrict__ bt1,
                const float* __restrict__ ysum, const ushort_t* __restrict__ W2t,
                ushort_t* __restrict__ z2H, float* __restrict__ stats2)
{
    __shared__ __align__(16) ushort_t sA[64 * 256];
    __shared__ __align__(16) float sAff[2 * D2];
    __shared__ __align__(16) float sYm[D2];
    const int t = threadIdx.x;
    {
        const float inv = 1.0f / (float)NN;
        const float mu = stats1[t] * inv;
        const float var = fmaf(-mu, mu, stats1[D2 + t] * inv);
        const float a = g1[t] * rsqrtf(var + BN_EPS);
        sAff[t] = a;
        sAff[D2 + t] = fmaf(-a, mu, bt1[t]);
        sYm[t] = ysum[t] * inv;
    }
    const int i0 = blockIdx.x * 64;
    const int lane = t & 63, w = t >> 6;
    const int nb = w * 32;

    f16x8 bfr[2][8];
    #pragma unroll
    for (int nt = 0; nt < 2; ++nt)
        #pragma unroll
        for (int ks = 0; ks < 8; ++ks) {
            const int n = nb + nt * 16 + (lane & 15);
            const int k = ks * 32 + (lane >> 4) * 8;
            bfr[nt][ks] = *(const f16x8*)&W2t[n * D2 + k];
        }
    __syncthreads();   // sAff/sYm visible

    #pragma unroll
    for (int p = 0; p < 8; ++p) {
        const int linear = p * 256 + t;
        const int row = linear >> 5, ch = linear & 31;
        const int gi = i0 + row;
        unsigned oo[4] = {0, 0, 0, 0};
        if (gi < NN) {
            const uint4 v = *(const uint4*)&z1H[(size_t)gi * D2 + ch * 8];
            const unsigned uu[4] = {v.x, v.y, v.z, v.w};
            #pragma unroll
            for (int j2 = 0; j2 < 4; ++j2) {
                const int c0 = ch * 8 + j2 * 2;
                float lo = h2f(uu[j2]);
                float hi = h2f(uu[j2] >> 16);
                lo = fmaxf(fmaf(sAff[c0], lo, sAff[D2 + c0]), 0.f) - sYm[c0];
                hi = fmaxf(fmaf(sAff[c0 + 1], hi, sAff[D2 + c0 + 1]), 0.f) - sYm[c0 + 1];
                oo[j2] = pk2h(lo, hi);
            }
        }
        unsigned boff = (unsigned)(row * 512 + ch * 16);
        boff ^= (unsigned)((row & 7) << 4);
        *(uint4*)((char*)sA + boff) = make_uint4(oo[0], oo[1], oo[2], oo[3]);
    }
    __syncthreads();

    f32x4 acc[4][2];
    #pragma unroll
    for (int a = 0; a < 4; ++a)
        #pragma unroll
        for (int b = 0; b < 2; ++b) acc[a][b] = (f32x4){0.f, 0.f, 0.f, 0.f};

    #pragma unroll
    for (int mt = 0; mt < 4; ++mt) {
        f16x8 af[8];
        #pragma unroll
        for (int ks = 0; ks < 8; ++ks) {
            const int row = mt * 16 + (lane & 15);
            unsigned boff = (unsigned)(row * 512 + ks * 64 + (lane >> 4) * 16);
            boff ^= (unsigned)((row & 7) << 4);
            af[ks] = *(const f16x8*)((const char*)sA + boff);
        }
        #pragma unroll
        for (int nt = 0; nt < 2; ++nt)
            #pragma unroll
            for (int ks = 0; ks < 8; ++ks)
                acc[mt][nt] = __builtin_amdgcn_mfma_f32_16x16x32_f16(af[ks], bfr[nt][ks], acc[mt][nt], 0, 0, 0);
    }

    float s[2], q[2];
    #pragma unroll
    for (int nt = 0; nt < 2; ++nt) { s[nt] = 0.f; q[nt] = 0.f; }
    #pragma unroll
    for (int nt = 0; nt < 2; ++nt) {
        const int n = nb + nt * 16 + (lane & 15);
        #pragma unroll
        for (int mt = 0; mt < 4; ++mt)
            #pragma unroll
            for (int r = 0; r < 4; ++r) {
                const int i = i0 + mt * 16 + (lane >> 4) * 4 + r;
                if (i < NN) {
                    const float v = acc[mt][nt][r];
                    s[nt] += v; q[nt] = fmaf(v, v, q[nt]);
                    z2H[(size_t)i * D + n] = f2h(v);
                }
            }
    }
    #pragma unroll
    for (int nt = 0; nt < 2; ++nt) {
        s[nt] += __shfl_xor(s[nt], 16, 64); s[nt] += __shfl_xor(s[nt], 32, 64);
        q[nt] += __shfl_xor(q[nt], 16, 64); q[nt] += __shfl_xor(q[nt], 32, 64);
    }
    if (lane < 16) {
        #pragma unroll
        for (int nt = 0; nt < 2; ++nt) {
            const int n = nb + nt * 16 + lane;
            atomAddF(&stats2[n], s[nt]);
            atomAddF(&stats2[D + n], q[nt]);
        }
    }
}

// ---------------- act: HALF=1: hAct(fp16) = relu(aff2(z2)); HALF=0: out(fp32) = aff2(z2) ----------------
template<int HALF>
__global__ __launch_bounds__(256)
void act_kernel(const ushort_t* __restrict__ z2H, const float* __restrict__ stats2,
                const float* __restrict__ g, const float* __restrict__ bt,
                void* __restrict__ dstv)
{
    __shared__ float sA[D], sC[D];
    const int t = threadIdx.x;
    if (t < D) {
        const float inv = 1.0f / (float)NN;
        const float mu = stats2[t] * inv;
        const float var = fmaf(-mu, mu, stats2[D + t] * inv);
        const float a = g[t] * rsqrtf(var + BN_EPS);
        sA[t] = a;
        sC[t] = fmaf(-a, mu, bt[t]);
    }
    __syncthreads();
    const int idx = blockIdx.x * 256 + t;  // 4-element index
    if (idx < NN * D / 4) {
        const int d0 = (idx * 4) & (D - 1);
        const uint2 v = *(const uint2*)&z2H[(size_t)idx * 4];
        float4 o;
        o.x = fmaf(sA[d0 + 0], h2f(v.x),       sC[d0 + 0]);
        o.y = fmaf(sA[d0 + 1], h2f(v.x >> 16), sC[d0 + 1]);
        o.z = fmaf(sA[d0 + 2], h2f(v.y),       sC[d0 + 2]);
        o.w = fmaf(sA[d0 + 3], h2f(v.y >> 16), sC[d0 + 3]);
        if (HALF) {
            o.x = fmaxf(o.x, 0.f); o.y = fmaxf(o.y, 0.f);
            o.z = fmaxf(o.z, 0.f); o.w = fmaxf(o.w, 0.f);
            uint2 pkd;
            pkd.x = pk2h(o.x, o.y);
            pkd.y = pk2h(o.z, o.w);
            *((uint2*)dstv + idx) = pkd;
        } else {
            *((float4*)dstv + idx) = o;
        }
    }
}

extern "C" void kernel_launch(void* const* d_in, const int* in_sizes, int n_in,
                              void* d_out, int out_size, void* d_ws, size_t ws_size,
                              hipStream_t stream)
{
    (void)in_sizes; (void)n_in; (void)out_size; (void)ws_size;
    const int*   ei       = (const int*)d_in[1];
    const float* ea       = (const float*)d_in[2];
    const float* node_emb = (const float*)d_in[3];
    const float* We       = (const float*)d_in[4];
    const float* be       = (const float*)d_in[5];
    const float* eps      = (const float*)d_in[6];
    const float* W1       = (const float*)d_in[7];
    const float* g1       = (const float*)d_in[9];
    const float* bt1      = (const float*)d_in[10];
    const float* W2       = (const float*)d_in[11];
    const float* gbn      = (const float*)d_in[13];
    const float* bbn      = (const float*)d_in[14];
    float* out = (float*)d_out;

    char* base = (char*)d_ws;
    size_t off = 0;
    auto alloc = [&](size_t bytes) -> void* {
        void* p = base + off;
        off = (off + bytes + 255) & ~(size_t)255;
        return p;
    };
    ushort_t* tmpH   = (ushort_t*)alloc((size_t)NN * D * 2);   // xin (gather->mm1), z2 (mm2->act)
    ushort_t* z1H    = (ushort_t*)alloc((size_t)NN * D2 * 2);
    ushort_t* hAct   = (ushort_t*)alloc((size_t)NN * D * 2);   // fp16 post-BN+relu h
    ushort_t* W1t    = (ushort_t*)alloc((size_t)NL * D * D2 * 2);
    ushort_t* W2t    = (ushort_t*)alloc((size_t)NL * D * D2 * 2);
    float*    red    = (float*)alloc(1152 * sizeof(float));
    float*    stats1 = red;            // 512
    float*    stats2 = red + 512;      // 256
    float*    xsum   = red + 768;      // 128
    float*    ysum   = red + 896;      // 256
    int*      counts = (int*)alloc((NN + 1) * sizeof(int));
    int*      offs   = (int*)alloc((NN + 1) * sizeof(int));
    int*      offmut = (int*)alloc(NN * sizeof(int));
    int*      perm   = (int*)alloc(NN * sizeof(int));
    int*      dbins  = (int*)alloc(DBINS * sizeof(int));
    int*      sSrc   = (int*)alloc((size_t)NE * sizeof(int));
    ushort_t* eaH    = (ushort_t*)alloc((size_t)NE * 8 * 2);

    // ---- CSR build + degree sort + weight conversion ----
    hipMemsetAsync(counts, 0, (NN + 1) * sizeof(int), stream);
    hipMemsetAsync(dbins, 0, DBINS * sizeof(int), stream);
    hist_kernel<<<(NE + 255) / 256, 256, 0, stream>>>(ei, counts);
    scan_kernel<<<1, 1024, 0, stream>>>(counts, offs);
    dhist_kernel<<<(NN + 255) / 256, 256, 0, stream>>>(counts, dbins);
    dscan_kernel<<<1, DBINS, 0, stream>>>(dbins, dbins);   // in-place exclusive scan
    dperm_kernel<<<(NN + 255) / 256, 256, 0, stream>>>(counts, dbins, perm);
    hipMemcpyAsync(offmut, offs, NN * sizeof(int), hipMemcpyDeviceToDevice, stream);
    scatter_kernel<<<(NE + 255) / 256, 256, 0, stream>>>(ei, ea, offmut, sSrc, eaH);
    wconv_kernel<<<(NL * D * D2 + 255) / 256, 256, 0, stream>>>(W1, W2, W1t, W2t);

    for (int l = 0; l < NL; ++l) {
        hipMemsetAsync(red, 0, 1152 * sizeof(float), stream);
        if (l == 0) {
            gather_kernel<1><<<6250, 256, 0, stream>>>(offs, sSrc, eaH, perm,
                                                       We + l * EF * D, be + l * D,
                                                       hAct, node_emb, eps + l, tmpH, xsum);
        } else {
            gather_kernel<0><<<6250, 256, 0, stream>>>(offs, sSrc, eaH, perm,
                                                       We + l * EF * D, be + l * D,
                                                       hAct, node_emb, eps + l, tmpH, xsum);
        }
        mm1_kernel<<<(NN + 63) / 64, 256, 0, stream>>>(tmpH, xsum, W1t + (size_t)l * D * D2,
                                                       z1H, stats1);
        ymean_kernel<<<256, 256, 0, stream>>>(z1H, stats1, g1 + l * D2, bt1 + l * D2, ysum);
        mm2_kernel<<<(NN + 63) / 64, 256, 0, stream>>>(z1H, stats1, g1 + l * D2, bt1 + l * D2,
                                                       ysum, W2t + (size_t)l * D * D2,
                                                       tmpH, stats2);
        if (l < NL - 1) {
            act_kernel<1><<<(NN * D / 4 + 255) / 256, 256, 0, stream>>>(
                tmpH, stats2, gbn + l * D, bbn + l * D, hAct);
        } else {
            act_kernel<0><<<(NN * D / 4 + 255) / 256, 256, 0, stream>>>(
                tmpH, stats2, gbn + l * D, bbn + l * D, out);
        }
    }
}

// Round 9
// 1777.842 us; speedup vs baseline: 1.4787x; 1.4787x over previous
//
#include <hip/hip_runtime.h>
#include <cstddef>

#define NN 100000
#define NE 1600000
#define D 128
#define D2 256
#define EF 7
#define NL 5
#define BN_EPS 1e-5f
#define GW 12500   // waves in gather; 8 nodes per wave

typedef unsigned short ushort_t;
typedef __attribute__((ext_vector_type(8))) _Float16 f16x8;
typedef __attribute__((ext_vector_type(2))) _Float16 h2v;
typedef __attribute__((ext_vector_type(4))) float f32x4;

__device__ __forceinline__ void atomAddF(float* p, float v) { unsafeAtomicAdd(p, v); }

__device__ __forceinline__ ushort_t f2h(float f) {
    return __builtin_bit_cast(ushort_t, (_Float16)f);
}
__device__ __forceinline__ unsigned pk2h(float lo, float hi) {
    return (unsigned)f2h(lo) | ((unsigned)f2h(hi) << 16);
}
__device__ __forceinline__ float h2f(unsigned u16) {
    return (float)__builtin_bit_cast(_Float16, (ushort_t)(u16 & 0xFFFFu));
}
__device__ __forceinline__ h2v u2h2(unsigned u) { return __builtin_bit_cast(h2v, u); }

// ---------------- CSR build ----------------
__global__ __launch_bounds__(256)
void hist_kernel(const int* __restrict__ ei, int* __restrict__ counts)
{
    const int e = blockIdx.x * 256 + threadIdx.x;
    if (e < NE) atomicAdd(&counts[ei[NE + e]], 1);
}

__global__ __launch_bounds__(1024)
void scan_kernel(const int* __restrict__ counts, int* __restrict__ offs)
{
    __shared__ int ssum[1024];
    const int t = threadIdx.x;
    const int per = (NN + 1023) / 1024;
    const int base = t * per;
    int local = 0;
    for (int j = 0; j < per; ++j) {
        const int i = base + j;
        if (i < NN) local += counts[i];
    }
    ssum[t] = local;
    __syncthreads();
    for (int off = 1; off < 1024; off <<= 1) {
        int v = 0;
        if (t >= off) v = ssum[t - off];
        __syncthreads();
        ssum[t] += v;
        __syncthreads();
    }
    int run = ssum[t] - local;
    for (int j = 0; j < per; ++j) {
        const int i = base + j;
        if (i < NN) { offs[i] = run; run += counts[i]; }
    }
    if (t == 1023) offs[NN] = NE;
}

// scatter edges into dst-sorted order; pack edge features fp16 [8] (7 used)
__global__ __launch_bounds__(256)
void scatter_kernel(const int* __restrict__ ei, const float* __restrict__ ea,
                    int* __restrict__ offmut, int* __restrict__ sSrc,
                    ushort_t* __restrict__ eaH)
{
    const int e = blockIdx.x * 256 + threadIdx.x;
    if (e < NE) {
        const int dst = ei[NE + e];
        const int pos = atomicAdd(&offmut[dst], 1);
        sSrc[pos] = ei[e];
        const float* eap = &ea[(size_t)e * EF];
        const unsigned o0 = pk2h(eap[0], eap[1]);
        const unsigned o1 = pk2h(eap[2], eap[3]);
        const unsigned o2 = pk2h(eap[4], eap[5]);
        const unsigned o3 = pk2h(eap[6], 0.f);
        *(uint4*)&eaH[(size_t)pos * 8] = make_uint4(o0, o1, o2, o3);
    }
}

// ---------------- weight convert: W1[l][k][n]->W1t[l][n][k] fp16, W2 same ----------------
__global__ __launch_bounds__(256)
void wconv_kernel(const float* __restrict__ W1, const float* __restrict__ W2,
                  ushort_t* __restrict__ W1t, ushort_t* __restrict__ W2t)
{
    const int idx = blockIdx.x * 256 + threadIdx.x;
    const int per = D * D2;
    if (idx < NL * per) {
        const int l = idx / per, r = idx % per;
        const int k1 = r / D2, n1 = r % D2;            // W1: [128][256]
        W1t[(size_t)l * per + n1 * D + k1] = f2h(W1[idx]);
        const int k2 = r / D, n2 = r % D;              // W2: [256][128]
        W2t[(size_t)l * per + n2 * D2 + k2] = f2h(W2[idx]);
    }
}

// ---------------- gather: xin[n] = (1+eps)*h(n) + sum_e relu(h(src)+ee) ----------------
// 8 nodes per wave iterated CONCURRENTLY (8-deep load MLP); packed fp16 edge MLP.
template<int L0>
__global__ __launch_bounds__(256)
void gather_kernel(const int* __restrict__ offs, const int* __restrict__ sSrc,
                   const ushort_t* __restrict__ eaH,
                   const float* __restrict__ We, const float* __restrict__ be,
                   const ushort_t* __restrict__ hAct, const float* __restrict__ h0,
                   const float* __restrict__ epsp,
                   ushort_t* __restrict__ xinH, float* __restrict__ xsum)
{
    __shared__ __align__(16) float sCS[4][D];
    const int lane = threadIdx.x & 63;
    const int w = threadIdx.x >> 6;
    const int wid = blockIdx.x * 4 + w;

    const float2* We2 = (const float2*)We;
    const unsigned* hU = (const unsigned*)hAct;   // 64 dwords per row
    unsigned* xU = (unsigned*)xinH;
    h2v wP[EF];
    #pragma unroll
    for (int k = 0; k < EF; ++k) {
        const float2 wf = We2[k * 64 + lane];
        wP[k] = (h2v){(_Float16)wf.x, (_Float16)wf.y};
    }
    h2v beP;
    {
        const float2 bf = ((const float2*)be)[lane];
        beP = (h2v){(_Float16)bf.x, (_Float16)bf.y};
    }
    float2 h0v = {0.f, 0.f};
    h2v h0P = (h2v){(_Float16)0.f, (_Float16)0.f};
    if (L0) {
        h0v = ((const float2*)h0)[lane];
        h0P = (h2v){(_Float16)h0v.x, (_Float16)h0v.y};
    }
    const float epsv = 1.0f + *epsp;
    const h2v zz = (h2v){(_Float16)0.f, (_Float16)0.f};

    int p4[8], e4[8];
    #pragma unroll
    for (int i = 0; i < 8; ++i) {
        const int n = wid + i * GW;                    // exact: 8*GW == NN
        p4[i] = __builtin_amdgcn_readfirstlane(offs[n]);
        e4[i] = __builtin_amdgcn_readfirstlane(offs[n + 1]);
    }
    int mx = 0;
    #pragma unroll
    for (int i = 0; i < 8; ++i) mx = max(mx, e4[i] - p4[i]);

    float2 acc[8];
    #pragma unroll
    for (int i = 0; i < 8; ++i) acc[i] = (float2){0.f, 0.f};

    for (int j = 0; j < mx; ++j) {
        unsigned hwd[8];
        uint4 ev4[8];
        bool on[8];
        #pragma unroll
        for (int i = 0; i < 8; ++i) {
            on[i] = p4[i] < e4[i];
            if (on[i]) {
                ev4[i] = *(const uint4*)&eaH[(size_t)p4[i] * 8];   // wave-uniform
                if (!L0) {
                    const int src = sSrc[p4[i]];                   // wave-uniform
                    hwd[i] = hU[(src << 6) + lane];
                }
            }
        }
        #pragma unroll
        for (int i = 0; i < 8; ++i) {
            if (on[i]) {
                const h2v e01 = u2h2(ev4[i].x);
                const h2v e23 = u2h2(ev4[i].y);
                const h2v e45 = u2h2(ev4[i].z);
                const h2v e6x = u2h2(ev4[i].w);
                h2v m = beP;
                m = __builtin_elementwise_fma(__builtin_shufflevector(e01, e01, 0, 0), wP[0], m);
                m = __builtin_elementwise_fma(__builtin_shufflevector(e01, e01, 1, 1), wP[1], m);
                m = __builtin_elementwise_fma(__builtin_shufflevector(e23, e23, 0, 0), wP[2], m);
                m = __builtin_elementwise_fma(__builtin_shufflevector(e23, e23, 1, 1), wP[3], m);
                m = __builtin_elementwise_fma(__builtin_shufflevector(e45, e45, 0, 0), wP[4], m);
                m = __builtin_elementwise_fma(__builtin_shufflevector(e45, e45, 1, 1), wP[5], m);
                m = __builtin_elementwise_fma(__builtin_shufflevector(e6x, e6x, 0, 0), wP[6], m);
                const h2v hh = L0 ? h0P : u2h2(hwd[i]);
                const h2v r = __builtin_elementwise_max(m + hh, zz);
                acc[i].x += (float)r.x;
                acc[i].y += (float)r.y;
                ++p4[i];
            }
        }
    }

    float2 cs = {0.f, 0.f};
    #pragma unroll
    for (int i = 0; i < 8; ++i) {
        const int n = wid + i * GW;
        float2 hs;
        if (L0) hs = h0v;
        else {
            const unsigned hv = hU[(n << 6) + lane];
            hs.x = h2f(hv); hs.y = h2f(hv >> 16);
        }
        float2 a = acc[i];
        a.x = fmaf(epsv, hs.x, a.x);
        a.y = fmaf(epsv, hs.y, a.y);
        cs.x += a.x; cs.y += a.y;
        xU[(n << 6) + lane] = pk2h(a.x, a.y);
    }
    sCS[w][2 * lane] = cs.x;
    sCS[w][2 * lane + 1] = cs.y;
    __syncthreads();
    if (threadIdx.x < D) {
        atomAddF(&xsum[threadIdx.x],
                 sCS[0][threadIdx.x] + sCS[1][threadIdx.x] +
                 sCS[2][threadIdx.x] + sCS[3][threadIdx.x]);
    }
}

// ---------------- mm1: z1c = (xin - colmean) @ W1 (fp16 MFMA), fused stats ----------------
__global__ __launch_bounds__(256, 2)
void mm1_kernel(const ushort_t* __restrict__ xinH, const float* __restrict__ xsum,
                const ushort_t* __restrict__ W1t,
                ushort_t* __restrict__ z1H, float* __restrict__ stats)
{
    __shared__ __align__(16) ushort_t sA[64 * 128];
    __shared__ __align__(16) float sM[D];
    const int t = threadIdx.x;
    if (t < D) sM[t] = xsum[t] * (1.0f / (float)NN);
    const int i0 = blockIdx.x * 64;
    const int lane = t & 63, w = t >> 6;
    const int nb = w * 64;

    f16x8 bfr[4][4];
    #pragma unroll
    for (int nt = 0; nt < 4; ++nt)
        #pragma unroll
        for (int ks = 0; ks < 4; ++ks) {
            const int n = nb + nt * 16 + (lane & 15);
            const int k = ks * 32 + (lane >> 4) * 8;
            bfr[nt][ks] = *(const f16x8*)&W1t[n * D + k];
        }
    __syncthreads();   // sM visible

    #pragma unroll
    for (int p = 0; p < 4; ++p) {
        const int linear = p * 256 + t;
        const int row = linear >> 4, ch = linear & 15;
        const int gi = i0 + row;
        unsigned oo[4] = {0, 0, 0, 0};
        if (gi < NN) {
            const uint4 v = *(const uint4*)&xinH[(size_t)gi * D + ch * 8];
            const unsigned uu[4] = {v.x, v.y, v.z, v.w};
            #pragma unroll
            for (int j2 = 0; j2 < 4; ++j2) {
                const int c0 = ch * 8 + j2 * 2;
                oo[j2] = pk2h(h2f(uu[j2]) - sM[c0], h2f(uu[j2] >> 16) - sM[c0 + 1]);
            }
        }
        unsigned boff = (unsigned)(row * 256 + ch * 16);
        boff ^= (unsigned)((row & 7) << 4);
        *(uint4*)((char*)sA + boff) = make_uint4(oo[0], oo[1], oo[2], oo[3]);
    }
    __syncthreads();

    f32x4 acc[4][4];
    #pragma unroll
    for (int a = 0; a < 4; ++a)
        #pragma unroll
        for (int b = 0; b < 4; ++b) acc[a][b] = (f32x4){0.f, 0.f, 0.f, 0.f};

    #pragma unroll
    for (int mt = 0; mt < 4; ++mt) {
        f16x8 af[4];
        #pragma unroll
        for (int ks = 0; ks < 4; ++ks) {
            const int row = mt * 16 + (lane & 15);
            unsigned boff = (unsigned)(row * 256 + ks * 64 + (lane >> 4) * 16);
            boff ^= (unsigned)((row & 7) << 4);
            af[ks] = *(const f16x8*)((const char*)sA + boff);
        }
        #pragma unroll
        for (int nt = 0; nt < 4; ++nt)
            #pragma unroll
            for (int ks = 0; ks < 4; ++ks)
                acc[mt][nt] = __builtin_amdgcn_mfma_f32_16x16x32_f16(af[ks], bfr[nt][ks], acc[mt][nt], 0, 0, 0);
    }

    float s[4], q[4];
    #pragma unroll
    for (int nt = 0; nt < 4; ++nt) { s[nt] = 0.f; q[nt] = 0.f; }
    #pragma unroll
    for (int nt = 0; nt < 4; ++nt) {
        const int n = nb + nt * 16 + (lane & 15);
        #pragma unroll
        for (int mt = 0; mt < 4; ++mt)
            #pragma unroll
            for (int r = 0; r < 4; ++r) {
                const int i = i0 + mt * 16 + (lane >> 4) * 4 + r;
                if (i < NN) {
                    const float v = acc[mt][nt][r];
                    s[nt] += v; q[nt] = fmaf(v, v, q[nt]);
                    z1H[(size_t)i * D2 + n] = f2h(v);
                }
            }
    }
    #pragma unroll
    for (int nt = 0; nt < 4; ++nt) {
        s[nt] += __shfl_xor(s[nt], 16, 64); s[nt] += __shfl_xor(s[nt], 32, 64);
        q[nt] += __shfl_xor(q[nt], 16, 64); q[nt] += __shfl_xor(q[nt], 32, 64);
    }
    if (lane < 16) {
        #pragma unroll
        for (int nt = 0; nt < 4; ++nt) {
            const int n = nb + nt * 16 + lane;
            atomAddF(&stats[n], s[nt]);
            atomAddF(&stats[D2 + n], q[nt]);
        }
    }
}

// ---------------- mm2: z2c = (relu(aff1(z1c)) - ym) @ W2 (fp16 MFMA), fp16 out ----------------
// ym = analytic E[relu(N(bt1, g1^2))] -- any constant is exact (compensated via stats2/BN);
// this one centers columns well enough for fp16 storage.
__global__ __launch_bounds__(256, 2)
void mm2_kernel(const ushort_t* __restrict__ z1H, const float* __restrict__ stats1,
                const float* __restrict__ g1, const float* __restrict__ bt1,
                const ushort_t* __restrict__ W2t,
                ushort_t* __restrict__ z2H, float* __restrict__ stats2)
{
    __shared__ __align__(16) ushort_t sA[64 * 256];
    __shared__ __align__(16) float sAff[2 * D2];
    __shared__ __align__(16) float sYm[D2];
    const int t = threadIdx.x;
    {
        const float inv = 1.0f / (float)NN;
        const float mu = stats1[t] * inv;
        const float var = fmaf(-mu, mu, stats1[D2 + t] * inv);
        const float a = g1[t] * rsqrtf(var + BN_EPS);
        sAff[t] = a;
        sAff[D2 + t] = fmaf(-a, mu, bt1[t]);
        const float m0 = bt1[t];
        const float sg = fabsf(g1[t]);
        float ym;
        if (sg > 1e-20f) {
            const float r = m0 / sg;
            const float Ph = 0.5f * (1.0f + erff(r * 0.70710678f));
            const float ph = 0.39894228f * expf(-0.5f * r * r);
            ym = m0 * Ph + sg * ph;
        } else {
            ym = fmaxf(m0, 0.f);
        }
        sYm[t] = ym;
    }
    const int i0 = blockIdx.x * 64;
    const int lane = t & 63, w = t >> 6;
    const int nb = w * 32;

    f16x8 bfr[2][8];
    #pragma unroll
    for (int nt = 0; nt < 2; ++nt)
        #pragma unroll
        for (int ks = 0; ks < 8; ++ks) {
            const int n = nb + nt * 16 + (lane & 15);
            const int k = ks * 32 + (lane >> 4) * 8;
            bfr[nt][ks] = *(const f16x8*)&W2t[n * D2 + k];
        }
    __syncthreads();   // sAff/sYm visible

    #pragma unroll
    for (int p = 0; p < 8; ++p) {
        const int linear = p * 256 + t;
        const int row = linear >> 5, ch = linear & 31;
        const int gi = i0 + row;
        unsigned oo[4] = {0, 0, 0, 0};
        if (gi < NN) {
            const uint4 v = *(const uint4*)&z1H[(size_t)gi * D2 + ch * 8];
            const unsigned uu[4] = {v.x, v.y, v.z, v.w};
            #pragma unroll
            for (int j2 = 0; j2 < 4; ++j2) {
                const int c0 = ch * 8 + j2 * 2;
                float lo = h2f(uu[j2]);
                float hi = h2f(uu[j2] >> 16);
                lo = fmaxf(fmaf(sAff[c0], lo, sAff[D2 + c0]), 0.f) - sYm[c0];
                hi = fmaxf(fmaf(sAff[c0 + 1], hi, sAff[D2 + c0 + 1]), 0.f) - sYm[c0 + 1];
                oo[j2] = pk2h(lo, hi);
            }
        }
        unsigned boff = (unsigned)(row * 512 + ch * 16);
        boff ^= (unsigned)((row & 7) << 4);
        *(uint4*)((char*)sA + boff) = make_uint4(oo[0], oo[1], oo[2], oo[3]);
    }
    __syncthreads();

    f32x4 acc[4][2];
    #pragma unroll
    for (int a = 0; a < 4; ++a)
        #pragma unroll
        for (int b = 0; b < 2; ++b) acc[a][b] = (f32x4){0.f, 0.f, 0.f, 0.f};

    #pragma unroll
    for (int mt = 0; mt < 4; ++mt) {
        f16x8 af[8];
        #pragma unroll
        for (int ks = 0; ks < 8; ++ks) {
            const int row = mt * 16 + (lane & 15);
            unsigned boff = (unsigned)(row * 512 + ks * 64 + (lane >> 4) * 16);
            boff ^= (unsigned)((row & 7) << 4);
            af[ks] = *(const f16x8*)((const char*)sA + boff);
        }
        #pragma unroll
        for (int nt = 0; nt < 2; ++nt)
            #pragma unroll
            for (int ks = 0; ks < 8; ++ks)
                acc[mt][nt] = __builtin_amdgcn_mfma_f32_16x16x32_f16(af[ks], bfr[nt][ks], acc[mt][nt], 0, 0, 0);
    }

    float s[2], q[2];
    #pragma unroll
    for (int nt = 0; nt < 2; ++nt) { s[nt] = 0.f; q[nt] = 0.f; }
    #pragma unroll
    for (int nt = 0; nt < 2; ++nt) {
        const int n = nb + nt * 16 + (lane & 15);
        #pragma unroll
        for (int mt = 0; mt < 4; ++mt)
            #pragma unroll
            for (int r = 0; r < 4; ++r) {
                const int i = i0 + mt * 16 + (lane >> 4) * 4 + r;
                if (i < NN) {
                    const float v = acc[mt][nt][r];
                    s[nt] += v; q[nt] = fmaf(v, v, q[nt]);
                    z2H[(size_t)i * D + n] = f2h(v);
                }
            }
    }
    #pragma unroll
    for (int nt = 0; nt < 2; ++nt) {
        s[nt] += __shfl_xor(s[nt], 16, 64); s[nt] += __shfl_xor(s[nt], 32, 64);
        q[nt] += __shfl_xor(q[nt], 16, 64); q[nt] += __shfl_xor(q[nt], 32, 64);
    }
    if (lane < 16) {
        #pragma unroll
        for (int nt = 0; nt < 2; ++nt) {
            const int n = nb + nt * 16 + lane;
            atomAddF(&stats2[n], s[nt]);
            atomAddF(&stats2[D + n], q[nt]);
        }
    }
}

// ---------------- act: HALF=1: hAct(fp16) = relu(aff2(z2)); HALF=0: out(fp32) = aff2(z2) ----------------
template<int HALF>
__global__ __launch_bounds__(256)
void act_kernel(const ushort_t* __restrict__ z2H, const float* __restrict__ stats2,
                const float* __restrict__ g, const float* __restrict__ bt,
                void* __restrict__ dstv)
{
    __shared__ float sA[D], sC[D];
    const int t = threadIdx.x;
    if (t < D) {
        const float inv = 1.0f / (float)NN;
        const float mu = stats2[t] * inv;
        const float var = fmaf(-mu, mu, stats2[D + t] * inv);
        const float a = g[t] * rsqrtf(var + BN_EPS);
        sA[t] = a;
        sC[t] = fmaf(-a, mu, bt[t]);
    }
    __syncthreads();
    const int idx = blockIdx.x * 256 + t;  // 4-element index
    if (idx < NN * D / 4) {
        const int d0 = (idx * 4) & (D - 1);
        const uint2 v = *(const uint2*)&z2H[(size_t)idx * 4];
        float4 o;
        o.x = fmaf(sA[d0 + 0], h2f(v.x),       sC[d0 + 0]);
        o.y = fmaf(sA[d0 + 1], h2f(v.x >> 16), sC[d0 + 1]);
        o.z = fmaf(sA[d0 + 2], h2f(v.y),       sC[d0 + 2]);
        o.w = fmaf(sA[d0 + 3], h2f(v.y >> 16), sC[d0 + 3]);
        if (HALF) {
            o.x = fmaxf(o.x, 0.f); o.y = fmaxf(o.y, 0.f);
            o.z = fmaxf(o.z, 0.f); o.w = fmaxf(o.w, 0.f);
            uint2 pkd;
            pkd.x = pk2h(o.x, o.y);
            pkd.y = pk2h(o.z, o.w);
            *((uint2*)dstv + idx) = pkd;
        } else {
            *((float4*)dstv + idx) = o;
        }
    }
}

extern "C" void kernel_launch(void* const* d_in, const int* in_sizes, int n_in,
                              void* d_out, int out_size, void* d_ws, size_t ws_size,
                              hipStream_t stream)
{
    (void)in_sizes; (void)n_in; (void)out_size; (void)ws_size;
    const int*   ei       = (const int*)d_in[1];
    const float* ea       = (const float*)d_in[2];
    const float* node_emb = (const float*)d_in[3];
    const float* We       = (const float*)d_in[4];
    const float* be       = (const float*)d_in[5];
    const float* eps      = (const float*)d_in[6];
    const float* W1       = (const float*)d_in[7];
    const float* g1       = (const float*)d_in[9];
    const float* bt1      = (const float*)d_in[10];
    const float* W2       = (const float*)d_in[11];
    const float* gbn      = (const float*)d_in[13];
    const float* bbn      = (const float*)d_in[14];
    float* out = (float*)d_out;

    char* base = (char*)d_ws;
    size_t off = 0;
    auto alloc = [&](size_t bytes) -> void* {
        void* p = base + off;
        off = (off + bytes + 255) & ~(size_t)255;
        return p;
    };
    ushort_t* tmpH   = (ushort_t*)alloc((size_t)NN * D * 2);   // xin (gather->mm1), z2 (mm2->act)
    ushort_t* z1H    = (ushort_t*)alloc((size_t)NN * D2 * 2);
    ushort_t* hAct   = (ushort_t*)alloc((size_t)NN * D * 2);   // fp16 post-BN+relu h
    ushort_t* W1t    = (ushort_t*)alloc((size_t)NL * D * D2 * 2);
    ushort_t* W2t    = (ushort_t*)alloc((size_t)NL * D * D2 * 2);
    float*    red    = (float*)alloc(896 * sizeof(float));
    float*    stats1 = red;            // 512
    float*    stats2 = red + 512;      // 256
    float*    xsum   = red + 768;      // 128
    int*      counts = (int*)alloc((NN + 1) * sizeof(int));
    int*      offs   = (int*)alloc((NN + 1) * sizeof(int));
    int*      offmut = (int*)alloc(NN * sizeof(int));
    int*      sSrc   = (int*)alloc((size_t)NE * sizeof(int));
    ushort_t* eaH    = (ushort_t*)alloc((size_t)NE * 8 * 2);

    // ---- CSR build + weight conversion ----
    hipMemsetAsync(counts, 0, (NN + 1) * sizeof(int), stream);
    hist_kernel<<<(NE + 255) / 256, 256, 0, stream>>>(ei, counts);
    scan_kernel<<<1, 1024, 0, stream>>>(counts, offs);
    hipMemcpyAsync(offmut, offs, NN * sizeof(int), hipMemcpyDeviceToDevice, stream);
    scatter_kernel<<<(NE + 255) / 256, 256, 0, stream>>>(ei, ea, offmut, sSrc, eaH);
    wconv_kernel<<<(NL * D * D2 + 255) / 256, 256, 0, stream>>>(W1, W2, W1t, W2t);

    for (int l = 0; l < NL; ++l) {
        hipMemsetAsync(red, 0, 896 * sizeof(float), stream);
        if (l == 0) {
            gather_kernel<1><<<GW / 4, 256, 0, stream>>>(offs, sSrc, eaH,
                                                         We + l * EF * D, be + l * D,
                                                         hAct, node_emb, eps + l, tmpH, xsum);
        } else {
            gather_kernel<0><<<GW / 4, 256, 0, stream>>>(offs, sSrc, eaH,
                                                         We + l * EF * D, be + l * D,
                                                         hAct, node_emb, eps + l, tmpH, xsum);
        }
        mm1_kernel<<<(NN + 63) / 64, 256, 0, stream>>>(tmpH, xsum, W1t + (size_t)l * D * D2,
                                                       z1H, stats1);
        mm2_kernel<<<(NN + 63) / 64, 256, 0, stream>>>(z1H, stats1, g1 + l * D2, bt1 + l * D2,
                                                       W2t + (size_t)l * D * D2,
                                                       tmpH, stats2);
        if (l < NL - 1) {
            act_kernel<1><<<(NN * D / 4 + 255) / 256, 256, 0, stream>>>(
                tmpH, stats2, gbn + l * D, bbn + l * D, hAct);
        } else {
            act_kernel<0><<<(NN * D / 4 + 255) / 256, 256, 0, stream>>>(
                tmpH, stats2, gbn + l * D, bbn + l * D, out);
        }
    }
}

// Round 10
// 1605.845 us; speedup vs baseline: 1.6371x; 1.1071x over previous
//
#include <hip/hip_runtime.h>
#include <cstddef>

#define NN 100000
#define NE 1600000
#define D 128
#define D2 256
#define EF 7
#define NL 5
#define BN_EPS 1e-5f
#define GW 12500   // waves in gather; 8 nodes per wave
#define SCAN_NB ((NN + 1023) / 1024)   // 98

typedef unsigned short ushort_t;
typedef __attribute__((ext_vector_type(8))) _Float16 f16x8;
typedef __attribute__((ext_vector_type(2))) _Float16 h2v;
typedef __attribute__((ext_vector_type(4))) float f32x4;

__device__ __forceinline__ void atomAddF(float* p, float v) { unsafeAtomicAdd(p, v); }

__device__ __forceinline__ ushort_t f2h(float f) {
    return __builtin_bit_cast(ushort_t, (_Float16)f);
}
__device__ __forceinline__ unsigned pk2h(float lo, float hi) {
    return (unsigned)f2h(lo) | ((unsigned)f2h(hi) << 16);
}
__device__ __forceinline__ float h2f(unsigned u16) {
    return (float)__builtin_bit_cast(_Float16, (ushort_t)(u16 & 0xFFFFu));
}
__device__ __forceinline__ h2v u2h2(unsigned u) { return __builtin_bit_cast(h2v, u); }

// ---------------- CSR build ----------------
__global__ __launch_bounds__(256)
void hist_kernel(const int* __restrict__ ei, int* __restrict__ counts)
{
    const int e = blockIdx.x * 256 + threadIdx.x;
    if (e < NE) atomicAdd(&counts[ei[NE + e]], 1);
}

// hierarchical scan: A) block sums
__global__ __launch_bounds__(256)
void scanA_kernel(const int* __restrict__ counts, int* __restrict__ bsum)
{
    __shared__ int sred[256];
    const int t = threadIdx.x;
    const int base = blockIdx.x * 1024 + t * 4;
    int s = 0;
    #pragma unroll
    for (int j = 0; j < 4; ++j) { const int i = base + j; if (i < NN) s += counts[i]; }
    sred[t] = s;
    __syncthreads();
    for (int off = 128; off > 0; off >>= 1) {
        if (t < off) sred[t] += sred[t + off];
        __syncthreads();
    }
    if (t == 0) bsum[blockIdx.x] = sred[0];
}

// B) scan the 98 block sums (one tiny block)
__global__ __launch_bounds__(128)
void scanB_kernel(const int* __restrict__ bsum, int* __restrict__ bbase,
                  int* __restrict__ offs)
{
    __shared__ int ss[128];
    const int t = threadIdx.x;
    const int v = (t < SCAN_NB) ? bsum[t] : 0;
    ss[t] = v;
    __syncthreads();
    for (int off = 1; off < 128; off <<= 1) {
        int u = 0;
        if (t >= off) u = ss[t - off];
        __syncthreads();
        ss[t] += u;
        __syncthreads();
    }
    if (t < SCAN_NB) bbase[t] = ss[t] - v;   // exclusive
    if (t == 0) offs[NN] = NE;
}

// C) local scan + base
__global__ __launch_bounds__(256)
void scanC_kernel(const int* __restrict__ counts, const int* __restrict__ bbase,
                  int* __restrict__ offs)
{
    __shared__ int sts[256];
    const int t = threadIdx.x;
    const int base = blockIdx.x * 1024 + t * 4;
    int c[4];
    int s = 0;
    #pragma unroll
    for (int j = 0; j < 4; ++j) {
        const int i = base + j;
        c[j] = (i < NN) ? counts[i] : 0;
        s += c[j];
    }
    sts[t] = s;
    __syncthreads();
    for (int off = 1; off < 256; off <<= 1) {
        int u = 0;
        if (t >= off) u = sts[t - off];
        __syncthreads();
        sts[t] += u;
        __syncthreads();
    }
    int run = bbase[blockIdx.x] + sts[t] - s;
    #pragma unroll
    for (int j = 0; j < 4; ++j) {
        const int i = base + j;
        if (i < NN) { offs[i] = run; run += c[j]; }
    }
}

// scatter edges into dst-sorted order; pack edge features fp16 [8] (7 used)
__global__ __launch_bounds__(256)
void scatter_kernel(const int* __restrict__ ei, const float* __restrict__ ea,
                    int* __restrict__ offmut, int* __restrict__ sSrc,
                    ushort_t* __restrict__ eaH)
{
    const int e = blockIdx.x * 256 + threadIdx.x;
    if (e < NE) {
        const int dst = ei[NE + e];
        const int pos = atomicAdd(&offmut[dst], 1);
        sSrc[pos] = ei[e];
        const float* eap = &ea[(size_t)e * EF];
        const unsigned o0 = pk2h(eap[0], eap[1]);
        const unsigned o1 = pk2h(eap[2], eap[3]);
        const unsigned o2 = pk2h(eap[4], eap[5]);
        const unsigned o3 = pk2h(eap[6], 0.f);
        *(uint4*)&eaH[(size_t)pos * 8] = make_uint4(o0, o1, o2, o3);
    }
}

// ---------------- weight convert: W1[l][k][n]->W1t[l][n][k] fp16, W2 same ----------------
__global__ __launch_bounds__(256)
void wconv_kernel(const float* __restrict__ W1, const float* __restrict__ W2,
                  ushort_t* __restrict__ W1t, ushort_t* __restrict__ W2t)
{
    const int idx = blockIdx.x * 256 + threadIdx.x;
    const int per = D * D2;
    if (idx < NL * per) {
        const int l = idx / per, r = idx % per;
        const int k1 = r / D2, n1 = r % D2;            // W1: [128][256]
        W1t[(size_t)l * per + n1 * D + k1] = f2h(W1[idx]);
        const int k2 = r / D, n2 = r % D;              // W2: [256][128]
        W2t[(size_t)l * per + n2 * D2 + k2] = f2h(W2[idx]);
    }
}

// ---------------- gather: xin[n] = (1+eps)*h(n) + sum_e relu(h(src)+ee) ----------------
// 8 nodes per wave iterated CONCURRENTLY (8-deep load MLP); packed fp16 edge MLP.
template<int L0>
__global__ __launch_bounds__(256)
void gather_kernel(const int* __restrict__ offs, const int* __restrict__ sSrc,
                   const ushort_t* __restrict__ eaH,
                   const float* __restrict__ We, const float* __restrict__ be,
                   const ushort_t* __restrict__ hAct, const float* __restrict__ h0,
                   const float* __restrict__ epsp,
                   ushort_t* __restrict__ xinH, float* __restrict__ xsum)
{
    __shared__ __align__(16) float sCS[4][D];
    const int lane = threadIdx.x & 63;
    const int w = threadIdx.x >> 6;
    const int wid = blockIdx.x * 4 + w;

    const float2* We2 = (const float2*)We;
    const unsigned* hU = (const unsigned*)hAct;   // 64 dwords per row
    unsigned* xU = (unsigned*)xinH;
    h2v wP[EF];
    #pragma unroll
    for (int k = 0; k < EF; ++k) {
        const float2 wf = We2[k * 64 + lane];
        wP[k] = (h2v){(_Float16)wf.x, (_Float16)wf.y};
    }
    h2v beP;
    {
        const float2 bf = ((const float2*)be)[lane];
        beP = (h2v){(_Float16)bf.x, (_Float16)bf.y};
    }
    float2 h0v = {0.f, 0.f};
    h2v h0P = (h2v){(_Float16)0.f, (_Float16)0.f};
    if (L0) {
        h0v = ((const float2*)h0)[lane];
        h0P = (h2v){(_Float16)h0v.x, (_Float16)h0v.y};
    }
    const float epsv = 1.0f + *epsp;
    const h2v zz = (h2v){(_Float16)0.f, (_Float16)0.f};

    int p4[8], e4[8];
    #pragma unroll
    for (int i = 0; i < 8; ++i) {
        const int n = wid + i * GW;                    // exact: 8*GW == NN
        p4[i] = __builtin_amdgcn_readfirstlane(offs[n]);
        e4[i] = __builtin_amdgcn_readfirstlane(offs[n + 1]);
    }
    int mx = 0;
    #pragma unroll
    for (int i = 0; i < 8; ++i) mx = max(mx, e4[i] - p4[i]);

    float2 acc[8];
    #pragma unroll
    for (int i = 0; i < 8; ++i) acc[i] = (float2){0.f, 0.f};

    for (int j = 0; j < mx; ++j) {
        unsigned hwd[8];
        uint4 ev4[8];
        bool on[8];
        #pragma unroll
        for (int i = 0; i < 8; ++i) {
            on[i] = p4[i] < e4[i];
            if (on[i]) {
                ev4[i] = *(const uint4*)&eaH[(size_t)p4[i] * 8];   // wave-uniform
                if (!L0) {
                    const int src = sSrc[p4[i]];                   // wave-uniform
                    hwd[i] = hU[(src << 6) + lane];
                }
            }
        }
        #pragma unroll
        for (int i = 0; i < 8; ++i) {
            if (on[i]) {
                const h2v e01 = u2h2(ev4[i].x);
                const h2v e23 = u2h2(ev4[i].y);
                const h2v e45 = u2h2(ev4[i].z);
                const h2v e6x = u2h2(ev4[i].w);
                h2v m = beP;
                m = __builtin_elementwise_fma(__builtin_shufflevector(e01, e01, 0, 0), wP[0], m);
                m = __builtin_elementwise_fma(__builtin_shufflevector(e01, e01, 1, 1), wP[1], m);
                m = __builtin_elementwise_fma(__builtin_shufflevector(e23, e23, 0, 0), wP[2], m);
                m = __builtin_elementwise_fma(__builtin_shufflevector(e23, e23, 1, 1), wP[3], m);
                m = __builtin_elementwise_fma(__builtin_shufflevector(e45, e45, 0, 0), wP[4], m);
                m = __builtin_elementwise_fma(__builtin_shufflevector(e45, e45, 1, 1), wP[5], m);
                m = __builtin_elementwise_fma(__builtin_shufflevector(e6x, e6x, 0, 0), wP[6], m);
                const h2v hh = L0 ? h0P : u2h2(hwd[i]);
                const h2v r = __builtin_elementwise_max(m + hh, zz);
                acc[i].x += (float)r.x;
                acc[i].y += (float)r.y;
                ++p4[i];
            }
        }
    }

    float2 cs = {0.f, 0.f};
    #pragma unroll
    for (int i = 0; i < 8; ++i) {
        const int n = wid + i * GW;
        float2 hs;
        if (L0) hs = h0v;
        else {
            const unsigned hv = hU[(n << 6) + lane];
            hs.x = h2f(hv); hs.y = h2f(hv >> 16);
        }
        float2 a = acc[i];
        a.x = fmaf(epsv, hs.x, a.x);
        a.y = fmaf(epsv, hs.y, a.y);
        cs.x += a.x; cs.y += a.y;
        xU[(n << 6) + lane] = pk2h(a.x, a.y);
    }
    sCS[w][2 * lane] = cs.x;
    sCS[w][2 * lane + 1] = cs.y;
    __syncthreads();
    if (threadIdx.x < D) {
        atomAddF(&xsum[threadIdx.x],
                 sCS[0][threadIdx.x] + sCS[1][threadIdx.x] +
                 sCS[2][threadIdx.x] + sCS[3][threadIdx.x]);
    }
}

// ---------------- mm1: z1c = (xin - colmean) @ W1 (fp16 MFMA), fused stats ----------------
__global__ __launch_bounds__(256, 2)
void mm1_kernel(const ushort_t* __restrict__ xinH, const float* __restrict__ xsum,
                const ushort_t* __restrict__ W1t,
                ushort_t* __restrict__ z1H, float* __restrict__ stats)
{
    __shared__ __align__(16) ushort_t sA[64 * 128];
    __shared__ __align__(16) float sM[D];
    const int t = threadIdx.x;
    if (t < D) sM[t] = xsum[t] * (1.0f / (float)NN);
    const int i0 = blockIdx.x * 64;
    const int lane = t & 63, w = t >> 6;
    const int nb = w * 64;

    f16x8 bfr[4][4];
    #pragma unroll
    for (int nt = 0; nt < 4; ++nt)
        #pragma unroll
        for (int ks = 0; ks < 4; ++ks) {
            const int n = nb + nt * 16 + (lane & 15);
            const int k = ks * 32 + (lane >> 4) * 8;
            bfr[nt][ks] = *(const f16x8*)&W1t[n * D + k];
        }
    __syncthreads();   // sM visible

    #pragma unroll
    for (int p = 0; p < 4; ++p) {
        const int linear = p * 256 + t;
        const int row = linear >> 4, ch = linear & 15;
        const int gi = i0 + row;
        unsigned oo[4] = {0, 0, 0, 0};
        if (gi < NN) {
            const uint4 v = *(const uint4*)&xinH[(size_t)gi * D + ch * 8];
            const unsigned uu[4] = {v.x, v.y, v.z, v.w};
            #pragma unroll
            for (int j2 = 0; j2 < 4; ++j2) {
                const int c0 = ch * 8 + j2 * 2;
                oo[j2] = pk2h(h2f(uu[j2]) - sM[c0], h2f(uu[j2] >> 16) - sM[c0 + 1]);
            }
        }
        unsigned boff = (unsigned)(row * 256 + ch * 16);
        boff ^= (unsigned)((row & 7) << 4);
        *(uint4*)((char*)sA + boff) = make_uint4(oo[0], oo[1], oo[2], oo[3]);
    }
    __syncthreads();

    f32x4 acc[4][4];
    #pragma unroll
    for (int a = 0; a < 4; ++a)
        #pragma unroll
        for (int b = 0; b < 4; ++b) acc[a][b] = (f32x4){0.f, 0.f, 0.f, 0.f};

    #pragma unroll
    for (int mt = 0; mt < 4; ++mt) {
        f16x8 af[4];
        #pragma unroll
        for (int ks = 0; ks < 4; ++ks) {
            const int row = mt * 16 + (lane & 15);
            unsigned boff = (unsigned)(row * 256 + ks * 64 + (lane >> 4) * 16);
            boff ^= (unsigned)((row & 7) << 4);
            af[ks] = *(const f16x8*)((const char*)sA + boff);
        }
        #pragma unroll
        for (int nt = 0; nt < 4; ++nt)
            #pragma unroll
            for (int ks = 0; ks < 4; ++ks)
                acc[mt][nt] = __builtin_amdgcn_mfma_f32_16x16x32_f16(af[ks], bfr[nt][ks], acc[mt][nt], 0, 0, 0);
    }

    float s[4], q[4];
    #pragma unroll
    for (int nt = 0; nt < 4; ++nt) { s[nt] = 0.f; q[nt] = 0.f; }
    #pragma unroll
    for (int nt = 0; nt < 4; ++nt) {
        const int n = nb + nt * 16 + (lane & 15);
        #pragma unroll
        for (int mt = 0; mt < 4; ++mt)
            #pragma unroll
            for (int r = 0; r < 4; ++r) {
                const int i = i0 + mt * 16 + (lane >> 4) * 4 + r;
                if (i < NN) {
                    const float v = acc[mt][nt][r];
                    s[nt] += v; q[nt] = fmaf(v, v, q[nt]);
                    z1H[(size_t)i * D2 + n] = f2h(v);
                }
            }
    }
    #pragma unroll
    for (int nt = 0; nt < 4; ++nt) {
        s[nt] += __shfl_xor(s[nt], 16, 64); s[nt] += __shfl_xor(s[nt], 32, 64);
        q[nt] += __shfl_xor(q[nt], 16, 64); q[nt] += __shfl_xor(q[nt], 32, 64);
    }
    if (lane < 16) {
        #pragma unroll
        for (int nt = 0; nt < 4; ++nt) {
            const int n = nb + nt * 16 + lane;
            atomAddF(&stats[n], s[nt]);
            atomAddF(&stats[D2 + n], q[nt]);
        }
    }
}

// ---------------- mm2: z2c = (relu(aff1(z1c)) - ym) @ W2 (fp16 MFMA), fp16 out ----------------
// ym = analytic E[relu(N(bt1, g1^2))] -- any constant is exact (compensated via stats2/BN).
__global__ __launch_bounds__(256, 2)
void mm2_kernel(const ushort_t* __restrict__ z1H, const float* __restrict__ stats1,
                const float* __restrict__ g1, const float* __restrict__ bt1,
                const ushort_t* __restrict__ W2t,
                ushort_t* __restrict__ z2H, float* __restrict__ stats2)
{
    __shared__ __align__(16) ushort_t sA[64 * 256];
    __shared__ __align__(16) float sAff[2 * D2];
    __shared__ __align__(16) float sYm[D2];
    const int t = threadIdx.x;
    {
        const float inv = 1.0f / (float)NN;
        const float mu = stats1[t] * inv;
        const float var = fmaf(-mu, mu, stats1[D2 + t] * inv);
        const float a = g1[t] * rsqrtf(var + BN_EPS);
        sAff[t] = a;
        sAff[D2 + t] = fmaf(-a, mu, bt1[t]);
        const float m0 = bt1[t];
        const float sg = fabsf(g1[t]);
        float ym;
        if (sg > 1e-20f) {
            const float r = m0 / sg;
            const float Ph = 0.5f * (1.0f + erff(r * 0.70710678f));
            const float ph = 0.39894228f * expf(-0.5f * r * r);
            ym = m0 * Ph + sg * ph;
        } else {
            ym = fmaxf(m0, 0.f);
        }
        sYm[t] = ym;
    }
    const int i0 = blockIdx.x * 64;
    const int lane = t & 63, w = t >> 6;
    const int nb = w * 32;

    f16x8 bfr[2][8];
    #pragma unroll
    for (int nt = 0; nt < 2; ++nt)
        #pragma unroll
        for (int ks = 0; ks < 8; ++ks) {
            const int n = nb + nt * 16 + (lane & 15);
            const int k = ks * 32 + (lane >> 4) * 8;
            bfr[nt][ks] = *(const f16x8*)&W2t[n * D2 + k];
        }
    __syncthreads();   // sAff/sYm visible

    #pragma unroll
    for (int p = 0; p < 8; ++p) {
        const int linear = p * 256 + t;
        const int row = linear >> 5, ch = linear & 31;
        const int gi = i0 + row;
        unsigned oo[4] = {0, 0, 0, 0};
        if (gi < NN) {
            const uint4 v = *(const uint4*)&z1H[(size_t)gi * D2 + ch * 8];
            const unsigned uu[4] = {v.x, v.y, v.z, v.w};
            #pragma unroll
            for (int j2 = 0; j2 < 4; ++j2) {
                const int c0 = ch * 8 + j2 * 2;
                float lo = h2f(uu[j2]);
                float hi = h2f(uu[j2] >> 16);
                lo = fmaxf(fmaf(sAff[c0], lo, sAff[D2 + c0]), 0.f) - sYm[c0];
                hi = fmaxf(fmaf(sAff[c0 + 1], hi, sAff[D2 + c0 + 1]), 0.f) - sYm[c0 + 1];
                oo[j2] = pk2h(lo, hi);
            }
        }
        unsigned boff = (unsigned)(row * 512 + ch * 16);
        boff ^= (unsigned)((row & 7) << 4);
        *(uint4*)((char*)sA + boff) = make_uint4(oo[0], oo[1], oo[2], oo[3]);
    }
    __syncthreads();

    f32x4 acc[4][2];
    #pragma unroll
    for (int a = 0; a < 4; ++a)
        #pragma unroll
        for (int b = 0; b < 2; ++b) acc[a][b] = (f32x4){0.f, 0.f, 0.f, 0.f};

    #pragma unroll
    for (int mt = 0; mt < 4; ++mt) {
        f16x8 af[8];
        #pragma unroll
        for (int ks = 0; ks < 8; ++ks) {
            const int row = mt * 16 + (lane & 15);
            unsigned boff = (unsigned)(row * 512 + ks * 64 + (lane >> 4) * 16);
            boff ^= (unsigned)((row & 7) << 4);
            af[ks] = *(const f16x8*)((const char*)sA + boff);
        }
        #pragma unroll
        for (int nt = 0; nt < 2; ++nt)
            #pragma unroll
            for (int ks = 0; ks < 8; ++ks)
                acc[mt][nt] = __builtin_amdgcn_mfma_f32_16x16x32_f16(af[ks], bfr[nt][ks], acc[mt][nt], 0, 0, 0);
    }

    float s[2], q[2];
    #pragma unroll
    for (int nt = 0; nt < 2; ++nt) { s[nt] = 0.f; q[nt] = 0.f; }
    #pragma unroll
    for (int nt = 0; nt < 2; ++nt) {
        const int n = nb + nt * 16 + (lane & 15);
        #pragma unroll
        for (int mt = 0; mt < 4; ++mt)
            #pragma unroll
            for (int r = 0; r < 4; ++r) {
                const int i = i0 + mt * 16 + (lane >> 4) * 4 + r;
                if (i < NN) {
                    const float v = acc[mt][nt][r];
                    s[nt] += v; q[nt] = fmaf(v, v, q[nt]);
                    z2H[(size_t)i * D + n] = f2h(v);
                }
            }
    }
    #pragma unroll
    for (int nt = 0; nt < 2; ++nt) {
        s[nt] += __shfl_xor(s[nt], 16, 64); s[nt] += __shfl_xor(s[nt], 32, 64);
        q[nt] += __shfl_xor(q[nt], 16, 64); q[nt] += __shfl_xor(q[nt], 32, 64);
    }
    if (lane < 16) {
        #pragma unroll
        for (int nt = 0; nt < 2; ++nt) {
            const int n = nb + nt * 16 + lane;
            atomAddF(&stats2[n], s[nt]);
            atomAddF(&stats2[D + n], q[nt]);
        }
    }
}

// ---------------- act: HALF=1: hAct(fp16) = relu(aff2(z2)); HALF=0: out(fp32) = aff2(z2) ----------------
template<int HALF>
__global__ __launch_bounds__(256)
void act_kernel(const ushort_t* __restrict__ z2H, const float* __restrict__ stats2,
                const float* __restrict__ g, const float* __restrict__ bt,
                void* __restrict__ dstv)
{
    __shared__ float sA[D], sC[D];
    const int t = threadIdx.x;
    if (t < D) {
        const float inv = 1.0f / (float)NN;
        const float mu = stats2[t] * inv;
        const float var = fmaf(-mu, mu, stats2[D + t] * inv);
        const float a = g[t] * rsqrtf(var + BN_EPS);
        sA[t] = a;
        sC[t] = fmaf(-a, mu, bt[t]);
    }
    __syncthreads();
    const int idx = blockIdx.x * 256 + t;  // 4-element index
    if (idx < NN * D / 4) {
        const int d0 = (idx * 4) & (D - 1);
        const uint2 v = *(const uint2*)&z2H[(size_t)idx * 4];
        float4 o;
        o.x = fmaf(sA[d0 + 0], h2f(v.x),       sC[d0 + 0]);
        o.y = fmaf(sA[d0 + 1], h2f(v.x >> 16), sC[d0 + 1]);
        o.z = fmaf(sA[d0 + 2], h2f(v.y),       sC[d0 + 2]);
        o.w = fmaf(sA[d0 + 3], h2f(v.y >> 16), sC[d0 + 3]);
        if (HALF) {
            o.x = fmaxf(o.x, 0.f); o.y = fmaxf(o.y, 0.f);
            o.z = fmaxf(o.z, 0.f); o.w = fmaxf(o.w, 0.f);
            uint2 pkd;
            pkd.x = pk2h(o.x, o.y);
            pkd.y = pk2h(o.z, o.w);
            *((uint2*)dstv + idx) = pkd;
        } else {
            *((float4*)dstv + idx) = o;
        }
    }
}

extern "C" void kernel_launch(void* const* d_in, const int* in_sizes, int n_in,
                              void* d_out, int out_size, void* d_ws, size_t ws_size,
                              hipStream_t stream)
{
    (void)in_sizes; (void)n_in; (void)out_size; (void)ws_size;
    const int*   ei       = (const int*)d_in[1];
    const float* ea       = (const float*)d_in[2];
    const float* node_emb = (const float*)d_in[3];
    const float* We       = (const float*)d_in[4];
    const float* be       = (const float*)d_in[5];
    const float* eps      = (const float*)d_in[6];
    const float* W1       = (const float*)d_in[7];
    const float* g1       = (const float*)d_in[9];
    const float* bt1      = (const float*)d_in[10];
    const float* W2       = (const float*)d_in[11];
    const float* gbn      = (const float*)d_in[13];
    const float* bbn      = (const float*)d_in[14];
    float* out = (float*)d_out;

    char* base = (char*)d_ws;
    size_t off = 0;
    auto alloc = [&](size_t bytes) -> void* {
        void* p = base + off;
        off = (off + bytes + 255) & ~(size_t)255;
        return p;
    };
    ushort_t* tmpH   = (ushort_t*)alloc((size_t)NN * D * 2);   // xin (gather->mm1), z2 (mm2->act)
    ushort_t* z1H    = (ushort_t*)alloc((size_t)NN * D2 * 2);
    ushort_t* hAct   = (ushort_t*)alloc((size_t)NN * D * 2);   // fp16 post-BN+relu h
    ushort_t* W1t    = (ushort_t*)alloc((size_t)NL * D * D2 * 2);
    ushort_t* W2t    = (ushort_t*)alloc((size_t)NL * D * D2 * 2);
    float*    red    = (float*)alloc(896 * sizeof(float));
    float*    stats1 = red;            // 512
    float*    stats2 = red + 512;      // 256
    float*    xsum   = red + 768;      // 128
    int*      counts = (int*)alloc((NN + 1) * sizeof(int));
    int*      offs   = (int*)alloc((NN + 1) * sizeof(int));
    int*      offmut = (int*)alloc(NN * sizeof(int));
    int*      bsum   = (int*)alloc(SCAN_NB * sizeof(int));
    int*      bbase  = (int*)alloc(SCAN_NB * sizeof(int));
    int*      sSrc   = (int*)alloc((size_t)NE * sizeof(int));
    ushort_t* eaH    = (ushort_t*)alloc((size_t)NE * 8 * 2);

    // ---- CSR build + weight conversion ----
    hipMemsetAsync(counts, 0, (NN + 1) * sizeof(int), stream);
    hist_kernel<<<(NE + 255) / 256, 256, 0, stream>>>(ei, counts);
    scanA_kernel<<<SCAN_NB, 256, 0, stream>>>(counts, bsum);
    scanB_kernel<<<1, 128, 0, stream>>>(bsum, bbase, offs);
    scanC_kernel<<<SCAN_NB, 256, 0, stream>>>(counts, bbase, offs);
    hipMemcpyAsync(offmut, offs, NN * sizeof(int), hipMemcpyDeviceToDevice, stream);
    scatter_kernel<<<(NE + 255) / 256, 256, 0, stream>>>(ei, ea, offmut, sSrc, eaH);
    wconv_kernel<<<(NL * D * D2 + 255) / 256, 256, 0, stream>>>(W1, W2, W1t, W2t);

    for (int l = 0; l < NL; ++l) {
        hipMemsetAsync(red, 0, 896 * sizeof(float), stream);
        if (l == 0) {
            gather_kernel<1><<<GW / 4, 256, 0, stream>>>(offs, sSrc, eaH,
                                                         We + l * EF * D, be + l * D,
                                                         hAct, node_emb, eps + l, tmpH, xsum);
        } else {
            gather_kernel<0><<<GW / 4, 256, 0, stream>>>(offs, sSrc, eaH,
                                                         We + l * EF * D, be + l * D,
                                                         hAct, node_emb, eps + l, tmpH, xsum);
        }
        mm1_kernel<<<(NN + 63) / 64, 256, 0, stream>>>(tmpH, xsum, W1t + (size_t)l * D * D2,
                                                       z1H, stats1);
        mm2_kernel<<<(NN + 63) / 64, 256, 0, stream>>>(z1H, stats1, g1 + l * D2, bt1 + l * D2,
                                                       W2t + (size_t)l * D * D2,
                                                       tmpH, stats2);
        if (l < NL - 1) {
            act_kernel<1><<<(NN * D / 4 + 255) / 256, 256, 0, stream>>>(
                tmpH, stats2, gbn + l * D, bbn + l * D, hAct);
        } else {
            act_kernel<0><<<(NN * D / 4 + 255) / 256, 256, 0, stream>>>(
                tmpH, stats2, gbn + l * D, bbn + l * D, out);
        }
    }
}

// Round 12
// 1556.457 us; speedup vs baseline: 1.6890x; 1.0317x over previous
//
#include <hip/hip_runtime.h>
#include <cstddef>

#define NN 100000
#define NE 1600000
#define D 128
#define D2 256
#define EF 7
#define NL 5
#define BN_EPS 1e-5f
#define GW 12500   // waves in gather; 8 nodes per wave
#define SCAN_NB ((NN + 1023) / 1024)   // 98

typedef unsigned short ushort_t;
typedef __attribute__((ext_vector_type(8))) _Float16 f16x8;
typedef __attribute__((ext_vector_type(2))) _Float16 h2v;
typedef __attribute__((ext_vector_type(4))) float f32x4;

__device__ __forceinline__ void atomAddF(float* p, float v) { unsafeAtomicAdd(p, v); }

__device__ __forceinline__ ushort_t f2h(float f) {
    return __builtin_bit_cast(ushort_t, (_Float16)f);
}
__device__ __forceinline__ unsigned pk2h(float lo, float hi) {
    return (unsigned)f2h(lo) | ((unsigned)f2h(hi) << 16);
}
__device__ __forceinline__ float h2f(unsigned u16) {
    return (float)__builtin_bit_cast(_Float16, (ushort_t)(u16 & 0xFFFFu));
}
__device__ __forceinline__ h2v u2h2(unsigned u) { return __builtin_bit_cast(h2v, u); }

// ---------------- CSR build ----------------
__global__ __launch_bounds__(256)
void hist_kernel(const int* __restrict__ ei, int* __restrict__ counts)
{
    const int e = blockIdx.x * 256 + threadIdx.x;
    if (e < NE) atomicAdd(&counts[ei[NE + e]], 1);
}

// hierarchical scan: A) block sums
__global__ __launch_bounds__(256)
void scanA_kernel(const int* __restrict__ counts, int* __restrict__ bsum)
{
    __shared__ int sred[256];
    const int t = threadIdx.x;
    const int base = blockIdx.x * 1024 + t * 4;
    int s = 0;
    #pragma unroll
    for (int j = 0; j < 4; ++j) { const int i = base + j; if (i < NN) s += counts[i]; }
    sred[t] = s;
    __syncthreads();
    for (int off = 128; off > 0; off >>= 1) {
        if (t < off) sred[t] += sred[t + off];
        __syncthreads();
    }
    if (t == 0) bsum[blockIdx.x] = sred[0];
}

// B) scan the 98 block sums (one tiny block)
__global__ __launch_bounds__(128)
void scanB_kernel(const int* __restrict__ bsum, int* __restrict__ bbase,
                  int* __restrict__ offs)
{
    __shared__ int ss[128];
    const int t = threadIdx.x;
    const int v = (t < SCAN_NB) ? bsum[t] : 0;
    ss[t] = v;
    __syncthreads();
    for (int off = 1; off < 128; off <<= 1) {
        int u = 0;
        if (t >= off) u = ss[t - off];
        __syncthreads();
        ss[t] += u;
        __syncthreads();
    }
    if (t < SCAN_NB) bbase[t] = ss[t] - v;   // exclusive
    if (t == 0) offs[NN] = NE;
}

// C) local scan + base; also writes offmut (scatter cursor copy)
__global__ __launch_bounds__(256)
void scanC_kernel(const int* __restrict__ counts, const int* __restrict__ bbase,
                  int* __restrict__ offs, int* __restrict__ offmut)
{
    __shared__ int sts[256];
    const int t = threadIdx.x;
    const int base = blockIdx.x * 1024 + t * 4;
    int c[4];
    int s = 0;
    #pragma unroll
    for (int j = 0; j < 4; ++j) {
        const int i = base + j;
        c[j] = (i < NN) ? counts[i] : 0;
        s += c[j];
    }
    sts[t] = s;
    __syncthreads();
    for (int off = 1; off < 256; off <<= 1) {
        int u = 0;
        if (t >= off) u = sts[t - off];
        __syncthreads();
        sts[t] += u;
        __syncthreads();
    }
    int run = bbase[blockIdx.x] + sts[t] - s;
    #pragma unroll
    for (int j = 0; j < 4; ++j) {
        const int i = base + j;
        if (i < NN) { offs[i] = run; offmut[i] = run; run += c[j]; }
    }
}

// scatter edges into dst-sorted order; pack edge features fp16 [8] (7 used)
__global__ __launch_bounds__(256)
void scatter_kernel(const int* __restrict__ ei, const float* __restrict__ ea,
                    int* __restrict__ offmut, int* __restrict__ sSrc,
                    ushort_t* __restrict__ eaH)
{
    const int e = blockIdx.x * 256 + threadIdx.x;
    if (e < NE) {
        const int dst = ei[NE + e];
        const int pos = atomicAdd(&offmut[dst], 1);
        sSrc[pos] = ei[e];
        const float* eap = &ea[(size_t)e * EF];
        const unsigned o0 = pk2h(eap[0], eap[1]);
        const unsigned o1 = pk2h(eap[2], eap[3]);
        const unsigned o2 = pk2h(eap[4], eap[5]);
        const unsigned o3 = pk2h(eap[6], 0.f);
        *(uint4*)&eaH[(size_t)pos * 8] = make_uint4(o0, o1, o2, o3);
    }
}

// ---------------- weight convert: W1[l][k][n]->W1t[l][n][k] fp16, W2 same ----------------
__global__ __launch_bounds__(256)
void wconv_kernel(const float* __restrict__ W1, const float* __restrict__ W2,
                  ushort_t* __restrict__ W1t, ushort_t* __restrict__ W2t)
{
    const int idx = blockIdx.x * 256 + threadIdx.x;
    const int per = D * D2;
    if (idx < NL * per) {
        const int l = idx / per, r = idx % per;
        const int k1 = r / D2, n1 = r % D2;            // W1: [128][256]
        W1t[(size_t)l * per + n1 * D + k1] = f2h(W1[idx]);
        const int k2 = r / D, n2 = r % D;              // W2: [256][128]
        W2t[(size_t)l * per + n2 * D2 + k2] = f2h(W2[idx]);
    }
}

// ---------------- gather: xin[n] = (1+eps)*h(n) + sum_e relu(h(src)+ee) ----------------
// h = relu(aff2(z2)) computed INLINE (packed fp16) from raw z2; 8 concurrent chains/wave.
template<int L0>
__global__ __launch_bounds__(256)
void gather_kernel(const int* __restrict__ offs, const int* __restrict__ sSrc,
                   const ushort_t* __restrict__ eaH,
                   const float* __restrict__ We, const float* __restrict__ be,
                   const ushort_t* __restrict__ z2H, const float* __restrict__ stats2p,
                   const float* __restrict__ gbn, const float* __restrict__ bbn,
                   const float* __restrict__ h0, const float* __restrict__ epsp,
                   ushort_t* __restrict__ xinH, float* __restrict__ xsum)
{
    __shared__ __align__(16) float sCS[4][D];
    const int lane = threadIdx.x & 63;
    const int w = threadIdx.x >> 6;
    const int wid = blockIdx.x * 4 + w;

    const float2* We2 = (const float2*)We;
    const unsigned* hU = (const unsigned*)z2H;   // 64 dwords per row
    unsigned* xU = (unsigned*)xinH;
    h2v wP[EF];
    #pragma unroll
    for (int k = 0; k < EF; ++k) {
        const float2 wf = We2[k * 64 + lane];
        wP[k] = (h2v){(_Float16)wf.x, (_Float16)wf.y};
    }
    h2v beP;
    {
        const float2 bf = ((const float2*)be)[lane];
        beP = (h2v){(_Float16)bf.x, (_Float16)bf.y};
    }
    float2 h0v = {0.f, 0.f};
    h2v h0P = (h2v){(_Float16)0.f, (_Float16)0.f};
    h2v aP = (h2v){(_Float16)0.f, (_Float16)0.f};
    h2v cP = (h2v){(_Float16)0.f, (_Float16)0.f};
    if (L0) {
        h0v = ((const float2*)h0)[lane];
        h0P = (h2v){(_Float16)h0v.x, (_Float16)h0v.y};
    } else {
        // per-lane BN affine for cols 2*lane, 2*lane+1 (from prev layer's stats)
        const float inv = 1.0f / (float)NN;
        const int c0i = 2 * lane, c1i = 2 * lane + 1;
        const float mu0 = stats2p[c0i] * inv;
        const float mu1 = stats2p[c1i] * inv;
        const float v0 = fmaf(-mu0, mu0, stats2p[D + c0i] * inv);
        const float v1 = fmaf(-mu1, mu1, stats2p[D + c1i] * inv);
        const float a0 = gbn[c0i] * rsqrtf(v0 + BN_EPS);
        const float a1 = gbn[c1i] * rsqrtf(v1 + BN_EPS);
        const float c0 = fmaf(-a0, mu0, bbn[c0i]);
        const float c1 = fmaf(-a1, mu1, bbn[c1i]);
        aP = (h2v){(_Float16)a0, (_Float16)a1};
        cP = (h2v){(_Float16)c0, (_Float16)c1};
    }
    const float epsv = 1.0f + *epsp;
    const h2v zz = (h2v){(_Float16)0.f, (_Float16)0.f};

    int p4[8], e4[8];
    #pragma unroll
    for (int i = 0; i < 8; ++i) {
        const int n = wid + i * GW;                    // exact: 8*GW == NN
        p4[i] = __builtin_amdgcn_readfirstlane(offs[n]);
        e4[i] = __builtin_amdgcn_readfirstlane(offs[n + 1]);
    }
    int mx = 0;
    #pragma unroll
    for (int i = 0; i < 8; ++i) mx = max(mx, e4[i] - p4[i]);

    float2 acc[8];
    #pragma unroll
    for (int i = 0; i < 8; ++i) acc[i] = (float2){0.f, 0.f};

    for (int j = 0; j < mx; ++j) {
        unsigned hwd[8];
        uint4 ev4[8];
        bool on[8];
        #pragma unroll
        for (int i = 0; i < 8; ++i) {
            on[i] = p4[i] < e4[i];
            if (on[i]) {
                ev4[i] = *(const uint4*)&eaH[(size_t)p4[i] * 8];   // wave-uniform
                if (!L0) {
                    const int src = sSrc[p4[i]];                   // wave-uniform
                    hwd[i] = hU[(src << 6) + lane];
                }
            }
        }
        #pragma unroll
        for (int i = 0; i < 8; ++i) {
            if (on[i]) {
                const h2v e01 = u2h2(ev4[i].x);
                const h2v e23 = u2h2(ev4[i].y);
                const h2v e45 = u2h2(ev4[i].z);
                const h2v e6x = u2h2(ev4[i].w);
                h2v m = beP;
                m = __builtin_elementwise_fma(__builtin_shufflevector(e01, e01, 0, 0), wP[0], m);
                m = __builtin_elementwise_fma(__builtin_shufflevector(e01, e01, 1, 1), wP[1], m);
                m = __builtin_elementwise_fma(__builtin_shufflevector(e23, e23, 0, 0), wP[2], m);
                m = __builtin_elementwise_fma(__builtin_shufflevector(e23, e23, 1, 1), wP[3], m);
                m = __builtin_elementwise_fma(__builtin_shufflevector(e45, e45, 0, 0), wP[4], m);
                m = __builtin_elementwise_fma(__builtin_shufflevector(e45, e45, 1, 1), wP[5], m);
                m = __builtin_elementwise_fma(__builtin_shufflevector(e6x, e6x, 0, 0), wP[6], m);
                h2v hh;
                if (L0) hh = h0P;
                else hh = __builtin_elementwise_max(
                         __builtin_elementwise_fma(aP, u2h2(hwd[i]), cP), zz);
                const h2v r = __builtin_elementwise_max(m + hh, zz);
                acc[i].x += (float)r.x;
                acc[i].y += (float)r.y;
                ++p4[i];
            }
        }
    }

    float2 cs = {0.f, 0.f};
    #pragma unroll
    for (int i = 0; i < 8; ++i) {
        const int n = wid + i * GW;
        float2 hs;
        if (L0) hs = h0v;
        else {
            const h2v hz = __builtin_elementwise_max(
                __builtin_elementwise_fma(aP, u2h2(hU[(n << 6) + lane]), cP), zz);
            hs.x = (float)hz.x; hs.y = (float)hz.y;
        }
        float2 a = acc[i];
        a.x = fmaf(epsv, hs.x, a.x);
        a.y = fmaf(epsv, hs.y, a.y);
        cs.x += a.x; cs.y += a.y;
        xU[(n << 6) + lane] = pk2h(a.x, a.y);
    }
    sCS[w][2 * lane] = cs.x;
    sCS[w][2 * lane + 1] = cs.y;
    __syncthreads();
    if (threadIdx.x < D) {
        atomAddF(&xsum[threadIdx.x],
                 sCS[0][threadIdx.x] + sCS[1][threadIdx.x] +
                 sCS[2][threadIdx.x] + sCS[3][threadIdx.x]);
    }
}

// ---------------- mm1: z1c = (xin - colmean) @ W1 (fp16 MFMA), fused stats ----------------
__global__ __launch_bounds__(256, 2)
void mm1_kernel(const ushort_t* __restrict__ xinH, const float* __restrict__ xsum,
                const ushort_t* __restrict__ W1t,
                ushort_t* __restrict__ z1H, float* __restrict__ stats)
{
    __shared__ __align__(16) ushort_t sA[64 * 128];
    __shared__ __align__(16) float sM[D];
    const int t = threadIdx.x;
    if (t < D) sM[t] = xsum[t] * (1.0f / (float)NN);
    const int i0 = blockIdx.x * 64;
    const int lane = t & 63, w = t >> 6;
    const int nb = w * 64;

    f16x8 bfr[4][4];
    #pragma unroll
    for (int nt = 0; nt < 4; ++nt)
        #pragma unroll
        for (int ks = 0; ks < 4; ++ks) {
            const int n = nb + nt * 16 + (lane & 15);
            const int k = ks * 32 + (lane >> 4) * 8;
            bfr[nt][ks] = *(const f16x8*)&W1t[n * D + k];
        }
    __syncthreads();   // sM visible

    #pragma unroll
    for (int p = 0; p < 4; ++p) {
        const int linear = p * 256 + t;
        const int row = linear >> 4, ch = linear & 15;
        const int gi = i0 + row;
        unsigned oo[4] = {0, 0, 0, 0};
        if (gi < NN) {
            const uint4 v = *(const uint4*)&xinH[(size_t)gi * D + ch * 8];
            const unsigned uu[4] = {v.x, v.y, v.z, v.w};
            #pragma unroll
            for (int j2 = 0; j2 < 4; ++j2) {
                const int c0 = ch * 8 + j2 * 2;
                oo[j2] = pk2h(h2f(uu[j2]) - sM[c0], h2f(uu[j2] >> 16) - sM[c0 + 1]);
            }
        }
        unsigned boff = (unsigned)(row * 256 + ch * 16);
        boff ^= (unsigned)((row & 7) << 4);
        *(uint4*)((char*)sA + boff) = make_uint4(oo[0], oo[1], oo[2], oo[3]);
    }
    __syncthreads();

    f32x4 acc[4][4];
    #pragma unroll
    for (int a = 0; a < 4; ++a)
        #pragma unroll
        for (int b = 0; b < 4; ++b) acc[a][b] = (f32x4){0.f, 0.f, 0.f, 0.f};

    #pragma unroll
    for (int mt = 0; mt < 4; ++mt) {
        f16x8 af[4];
        #pragma unroll
        for (int ks = 0; ks < 4; ++ks) {
            const int row = mt * 16 + (lane & 15);
            unsigned boff = (unsigned)(row * 256 + ks * 64 + (lane >> 4) * 16);
            boff ^= (unsigned)((row & 7) << 4);
            af[ks] = *(const f16x8*)((const char*)sA + boff);
        }
        #pragma unroll
        for (int nt = 0; nt < 4; ++nt)
            #pragma unroll
            for (int ks = 0; ks < 4; ++ks)
                acc[mt][nt] = __builtin_amdgcn_mfma_f32_16x16x32_f16(af[ks], bfr[nt][ks], acc[mt][nt], 0, 0, 0);
    }

    float s[4], q[4];
    #pragma unroll
    for (int nt = 0; nt < 4; ++nt) { s[nt] = 0.f; q[nt] = 0.f; }
    #pragma unroll
    for (int nt = 0; nt < 4; ++nt) {
        const int n = nb + nt * 16 + (lane & 15);
        #pragma unroll
        for (int mt = 0; mt < 4; ++mt)
            #pragma unroll
            for (int r = 0; r < 4; ++r) {
                const int i = i0 + mt * 16 + (lane >> 4) * 4 + r;
                if (i < NN) {
                    const float v = acc[mt][nt][r];
                    s[nt] += v; q[nt] = fmaf(v, v, q[nt]);
                    z1H[(size_t)i * D2 + n] = f2h(v);
                }
            }
    }
    #pragma unroll
    for (int nt = 0; nt < 4; ++nt) {
        s[nt] += __shfl_xor(s[nt], 16, 64); s[nt] += __shfl_xor(s[nt], 32, 64);
        q[nt] += __shfl_xor(q[nt], 16, 64); q[nt] += __shfl_xor(q[nt], 32, 64);
    }
    if (lane < 16) {
        #pragma unroll
        for (int nt = 0; nt < 4; ++nt) {
            const int n = nb + nt * 16 + lane;
            atomAddF(&stats[n], s[nt]);
            atomAddF(&stats[D2 + n], q[nt]);
        }
    }
}

// ---------------- mm2: z2c = (relu(aff1(z1c)) - ym) @ W2 (fp16 MFMA), fp16 out ----------------
// ym = analytic E[relu(N(bt1, g1^2))] -- any constant is exact (compensated via stats2/BN).
__global__ __launch_bounds__(256, 2)
void mm2_kernel(const ushort_t* __restrict__ z1H, const float* __restrict__ stats1,
                const float* __restrict__ g1, const float* __restrict__ bt1,
                const ushort_t* __restrict__ W2t,
                ushort_t* __restrict__ z2H, float* __restrict__ stats2)
{
    __shared__ __align__(16) ushort_t sA[64 * 256];
    __shared__ __align__(16) float sAff[2 * D2];
    __shared__ __align__(16) float sYm[D2];
    const int t = threadIdx.x;
    {
        const float inv = 1.0f / (float)NN;
        const float mu = stats1[t] * inv;
        const float var = fmaf(-mu, mu, stats1[D2 + t] * inv);
        const float a = g1[t] * rsqrtf(var + BN_EPS);
        sAff[t] = a;
        sAff[D2 + t] = fmaf(-a, mu, bt1[t]);
        const float m0 = bt1[t];
        const float sg = fabsf(g1[t]);
        float ym;
        if (sg > 1e-20f) {
            const float r = m0 / sg;
            const float Ph = 0.5f * (1.0f + erff(r * 0.70710678f));
            const float ph = 0.39894228f * expf(-0.5f * r * r);
            ym = m0 * Ph + sg * ph;
        } else {
            ym = fmaxf(m0, 0.f);
        }
        sYm[t] = ym;
    }
    const int i0 = blockIdx.x * 64;
    const int lane = t & 63, w = t >> 6;
    const int nb = w * 32;

    f16x8 bfr[2][8];
    #pragma unroll
    for (int nt = 0; nt < 2; ++nt)
        #pragma unroll
        for (int ks = 0; ks < 8; ++ks) {
            const int n = nb + nt * 16 + (lane & 15);
            const int k = ks * 32 + (lane >> 4) * 8;
            bfr[nt][ks] = *(const f16x8*)&W2t[n * D2 + k];
        }
    __syncthreads();   // sAff/sYm visible

    #pragma unroll
    for (int p = 0; p < 8; ++p) {
        const int linear = p * 256 + t;
        const int row = linear >> 5, ch = linear & 31;
        const int gi = i0 + row;
        unsigned oo[4] = {0, 0, 0, 0};
        if (gi < NN) {
            const uint4 v = *(const uint4*)&z1H[(size_t)gi * D2 + ch * 8];
            const unsigned uu[4] = {v.x, v.y, v.z, v.w};
            #pragma unroll
            for (int j2 = 0; j2 < 4; ++j2) {
                const int c0 = ch * 8 + j2 * 2;
                float lo = h2f(uu[j2]);
                float hi = h2f(uu[j2] >> 16);
                lo = fmaxf(fmaf(sAff[c0], lo, sAff[D2 + c0]), 0.f) - sYm[c0];
                hi = fmaxf(fmaf(sAff[c0 + 1], hi, sAff[D2 + c0 + 1]), 0.f) - sYm[c0 + 1];
                oo[j2] = pk2h(lo, hi);
            }
        }
        unsigned boff = (unsigned)(row * 512 + ch * 16);
        boff ^= (unsigned)((row & 7) << 4);
        *(uint4*)((char*)sA + boff) = make_uint4(oo[0], oo[1], oo[2], oo[3]);
    }
    __syncthreads();

    f32x4 acc[4][2];
    #pragma unroll
    for (int a = 0; a < 4; ++a)
        #pragma unroll
        for (int b = 0; b < 2; ++b) acc[a][b] = (f32x4){0.f, 0.f, 0.f, 0.f};

    #pragma unroll
    for (int mt = 0; mt < 4; ++mt) {
        f16x8 af[8];
        #pragma unroll
        for (int ks = 0; ks < 8; ++ks) {
            const int row = mt * 16 + (lane & 15);
            unsigned boff = (unsigned)(row * 512 + ks * 64 + (lane >> 4) * 16);
            boff ^= (unsigned)((row & 7) << 4);
            af[ks] = *(const f16x8*)((const char*)sA + boff);
        }
        #pragma unroll
        for (int nt = 0; nt < 2; ++nt)
            #pragma unroll
            for (int ks = 0; ks < 8; ++ks)
                acc[mt][nt] = __builtin_amdgcn_mfma_f32_16x16x32_f16(af[ks], bfr[nt][ks], acc[mt][nt], 0, 0, 0);
    }

    float s[2], q[2];
    #pragma unroll
    for (int nt = 0; nt < 2; ++nt) { s[nt] = 0.f; q[nt] = 0.f; }
    #pragma unroll
    for (int nt = 0; nt < 2; ++nt) {
        const int n = nb + nt * 16 + (lane & 15);
        #pragma unroll
        for (int mt = 0; mt < 4; ++mt)
            #pragma unroll
            for (int r = 0; r < 4; ++r) {
                const int i = i0 + mt * 16 + (lane >> 4) * 4 + r;
                if (i < NN) {
                    const float v = acc[mt][nt][r];
                    s[nt] += v; q[nt] = fmaf(v, v, q[nt]);
                    z2H[(size_t)i * D + n] = f2h(v);
                }
            }
    }
    #pragma unroll
    for (int nt = 0; nt < 2; ++nt) {
        s[nt] += __shfl_xor(s[nt], 16, 64); s[nt] += __shfl_xor(s[nt], 32, 64);
        q[nt] += __shfl_xor(q[nt], 16, 64); q[nt] += __shfl_xor(q[nt], 32, 64);
    }
    if (lane < 16) {
        #pragma unroll
        for (int nt = 0; nt < 2; ++nt) {
            const int n = nb + nt * 16 + lane;
            atomAddF(&stats2[n], s[nt]);
            atomAddF(&stats2[D + n], q[nt]);
        }
    }
}

// ---------------- final act: out(fp32) = aff2(z2) ----------------
__global__ __launch_bounds__(256)
void act_kernel(const ushort_t* __restrict__ z2H, const float* __restrict__ stats2,
                const float* __restrict__ g, const float* __restrict__ bt,
                float* __restrict__ out)
{
    __shared__ float sA[D], sC[D];
    const int t = threadIdx.x;
    if (t < D) {
        const float inv = 1.0f / (float)NN;
        const float mu = stats2[t] * inv;
        const float var = fmaf(-mu, mu, stats2[D + t] * inv);
        const float a = g[t] * rsqrtf(var + BN_EPS);
        sA[t] = a;
        sC[t] = fmaf(-a, mu, bt[t]);
    }
    __syncthreads();
    const int idx = blockIdx.x * 256 + t;  // 4-element index
    if (idx < NN * D / 4) {
        const int d0 = (idx * 4) & (D - 1);
        const uint2 v = *(const uint2*)&z2H[(size_t)idx * 4];
        float4 o;
        o.x = fmaf(sA[d0 + 0], h2f(v.x),       sC[d0 + 0]);
        o.y = fmaf(sA[d0 + 1], h2f(v.x >> 16), sC[d0 + 1]);
        o.z = fmaf(sA[d0 + 2], h2f(v.y),       sC[d0 + 2]);
        o.w = fmaf(sA[d0 + 3], h2f(v.y >> 16), sC[d0 + 3]);
        *(float4*)&out[(size_t)idx * 4] = o;
    }
}

extern "C" void kernel_launch(void* const* d_in, const int* in_sizes, int n_in,
                              void* d_out, int out_size, void* d_ws, size_t ws_size,
                              hipStream_t stream)
{
    (void)in_sizes; (void)n_in; (void)out_size; (void)ws_size;
    const int*   ei       = (const int*)d_in[1];
    const float* ea       = (const float*)d_in[2];
    const float* node_emb = (const float*)d_in[3];
    const float* We       = (const float*)d_in[4];
    const float* be       = (const float*)d_in[5];
    const float* eps      = (const float*)d_in[6];
    const float* W1       = (const float*)d_in[7];
    const float* g1       = (const float*)d_in[9];
    const float* bt1      = (const float*)d_in[10];
    const float* W2       = (const float*)d_in[11];
    const float* gbn      = (const float*)d_in[13];
    const float* bbn      = (const float*)d_in[14];
    float* out = (float*)d_out;

    char* base = (char*)d_ws;
    size_t off = 0;
    auto alloc = [&](size_t bytes) -> void* {
        void* p = base + off;
        off = (off + bytes + 255) & ~(size_t)255;
        return p;
    };
    ushort_t* xinH   = (ushort_t*)alloc((size_t)NN * D * 2);
    ushort_t* z1H    = (ushort_t*)alloc((size_t)NN * D2 * 2);
    ushort_t* z2H    = (ushort_t*)alloc((size_t)NN * D * 2);
    ushort_t* W1t    = (ushort_t*)alloc((size_t)NL * D * D2 * 2);
    ushort_t* W2t    = (ushort_t*)alloc((size_t)NL * D * D2 * 2);
    // per-layer stats: [stats1(512) | stats2(256) | xsum(128)] = 896 floats per layer
    float*    red    = (float*)alloc((size_t)NL * 896 * sizeof(float));
    int*      counts = (int*)alloc((NN + 1) * sizeof(int));
    int*      offs   = (int*)alloc((NN + 1) * sizeof(int));
    int*      offmut = (int*)alloc(NN * sizeof(int));
    int*      bsum   = (int*)alloc(SCAN_NB * sizeof(int));
    int*      bbase  = (int*)alloc(SCAN_NB * sizeof(int));
    int*      sSrc   = (int*)alloc((size_t)NE * sizeof(int));
    ushort_t* eaH    = (ushort_t*)alloc((size_t)NE * 8 * 2);

    // ---- CSR build + weight conversion ----
    hipMemsetAsync(counts, 0, (NN + 1) * sizeof(int), stream);
    hipMemsetAsync(red, 0, (size_t)NL * 896 * sizeof(float), stream);
    hist_kernel<<<(NE + 255) / 256, 256, 0, stream>>>(ei, counts);
    scanA_kernel<<<SCAN_NB, 256, 0, stream>>>(counts, bsum);
    scanB_kernel<<<1, 128, 0, stream>>>(bsum, bbase, offs);
    scanC_kernel<<<SCAN_NB, 256, 0, stream>>>(counts, bbase, offs, offmut);
    scatter_kernel<<<(NE + 255) / 256, 256, 0, stream>>>(ei, ea, offmut, sSrc, eaH);
    wconv_kernel<<<(NL * D * D2 + 255) / 256, 256, 0, stream>>>(W1, W2, W1t, W2t);

    for (int l = 0; l < NL; ++l) {
        float* redl   = red + (size_t)l * 896;
        float* stats1 = redl;
        float* stats2 = redl + 512;
        float* xsum   = redl + 768;
        if (l == 0) {
            gather_kernel<1><<<GW / 4, 256, 0, stream>>>(offs, sSrc, eaH,
                We + l * EF * D, be + l * D,
                z2H, nullptr, nullptr, nullptr,
                node_emb, eps + l, xinH, xsum);
        } else {
            const float* stats2p = red + (size_t)(l - 1) * 896 + 512;
            gather_kernel<0><<<GW / 4, 256, 0, stream>>>(offs, sSrc, eaH,
                We + l * EF * D, be + l * D,
                z2H, stats2p, gbn + (l - 1) * D, bbn + (l - 1) * D,
                node_emb, eps + l, xinH, xsum);
        }
        mm1_kernel<<<(NN + 63) / 64, 256, 0, stream>>>(xinH, xsum, W1t + (size_t)l * D * D2,
                                                       z1H, stats1);
        mm2_kernel<<<(NN + 63) / 64, 256, 0, stream>>>(z1H, stats1, g1 + l * D2, bt1 + l * D2,
                                                       W2t + (size_t)l * D * D2,
                                                       z2H, stats2);
    }
    act_kernel<<<(NN * D / 4 + 255) / 256, 256, 0, stream>>>(
        z2H, red + (size_t)(NL - 1) * 896 + 512, gbn + (NL - 1) * D, bbn + (NL - 1) * D, out);
}